// Round 15
// baseline (232.295 us; speedup 1.0000x reference)
//
#include <hip/hip_runtime.h>
#include <math.h>

constexpr int Bn = 8, Cn = 64, Hn = 128, Wn = 128;
constexpr int HW  = Hn * Wn;      // 16384
constexpr int CHW = Cn * HW;      // 1048576
constexpr size_t NB = (size_t)Bn * CHW;   // elems per blocked tensor

typedef float  f32x4  __attribute__((ext_vector_type(4)));
typedef __bf16 bf16x8 __attribute__((ext_vector_type(8)));
typedef unsigned int u32x4 __attribute__((ext_vector_type(4)));
typedef unsigned int u32x2 __attribute__((ext_vector_type(2)));

static __device__ __forceinline__ unsigned short f2bf(float f) {
    unsigned u = __builtin_bit_cast(unsigned, f);
    u = (u + 0x7FFF + ((u >> 16) & 1)) >> 16;
    return (unsigned short)u;
}
static __device__ __forceinline__ float bf2f(unsigned short v) {
    unsigned u = (unsigned)v << 16;
    return __builtin_bit_cast(float, u);
}
static __device__ __forceinline__ float bfhalf(unsigned u, int hi) {
    unsigned r = hi ? (u & 0xffff0000u) : (u << 16);
    return __builtin_bit_cast(float, r);
}

// async global->LDS 16B (direct-to-shared); falls back to reg copy if unavailable
static __device__ __forceinline__ void gl_lds16(const unsigned short* g, unsigned short* l) {
#if defined(__has_builtin) && __has_builtin(__builtin_amdgcn_global_load_lds)
    __builtin_amdgcn_global_load_lds(
        (const __attribute__((address_space(1))) void*)g,
        (__attribute__((address_space(3))) void*)l, 16, 0, 0);
#else
    *(u32x4*)l = *(const u32x4*)g;
#endif
}

// ---------------- weight prep: OIHW fp32 -> [kk][s][t][co][8cj] bf16 ----------------
__global__ void prep_w_k(const float* __restrict__ W0, const float* __restrict__ W1,
                         const float* __restrict__ W2, const float* __restrict__ W3,
                         const float* __restrict__ W4, const float* __restrict__ W5,
                         unsigned short* __restrict__ dst) {
    int i = blockIdx.x * 256 + threadIdx.x;
    if (i >= 36864) return;
    const float* W = W0;
    switch (blockIdx.y) {
        case 1: W = W1; break; case 2: W = W2; break;
        case 3: W = W3; break; case 4: W = W4; break; case 5: W = W5; break;
        default: break;
    }
    int cj = i & 7;
    int rest = i >> 3;
    int co = rest & 63;
    rest >>= 6;              // (kk*4+s)*9 + t
    int t  = rest % 9;
    int hs = rest / 9;       // 0..7
    int ci = hs * 8 + cj;
    dst[(size_t)blockIdx.y * 36864 + i] = f2bf(W[(co * 64 + ci) * 9 + t]);
}

// ---------------- prep2: G2/Fw -> bf16; zero-page + w0 accumulator init ----------
__global__ void prep2_k(const float* __restrict__ G2, const float* __restrict__ Fw,
                        unsigned short* __restrict__ G2p, unsigned short* __restrict__ Fwp,
                        unsigned short* __restrict__ zp, float* __restrict__ w0z) {
    int i = blockIdx.x * 256 + threadIdx.x;
    if (i < 64) zp[i] = 0;
    if (i < 512) w0z[i] = 0.f;
    if (i < 36864) G2p[i] = f2bf(G2[i]);
    else if (i < 36864 + 16384) Fwp[i - 36864] = f2bf(Fw[i - 36864]);
}

// ---------------- pre: blocked bf16 of f_event and f_blur ----------
__global__ void pre_blk_k(const float* __restrict__ fe, const float* __restrict__ fb,
                          unsigned short* __restrict__ evb, unsigned short* __restrict__ fbb) {
    int i = blockIdx.x * 256 + threadIdx.x;       // (b, oct, px)
    int px = i & 16383;
    int oct = (i >> 14) & 7;
    int b = i >> 17;
    const float* pe = fe + (size_t)b * CHW + (size_t)oct * 8 * HW + px;
    const float* pb = fb + (size_t)b * CHW + (size_t)oct * 8 * HW + px;
    u32x4 ev, fbv;
#pragma unroll
    for (int q = 0; q < 4; ++q) {
        float e0 = pe[(size_t)(2 * q) * HW],     b0 = pb[(size_t)(2 * q) * HW];
        float e1 = pe[(size_t)(2 * q + 1) * HW], b1 = pb[(size_t)(2 * q + 1) * HW];
        ev[q]  = (unsigned)f2bf(e0) | ((unsigned)f2bf(e1) << 16);
        fbv[q] = (unsigned)f2bf(b0) | ((unsigned)f2bf(b1) << 16);
    }
    const size_t o = ((size_t)(b * 8 + oct) * HW + px) * 8;
    *(u32x4*)(evb + o) = ev;
    *(u32x4*)(fbb + o) = fbv;
}

// ---------------- L1: three independent RELU convs in one launch -------------------
// sel0: t1 = relu(conv(ev+fb, Wt1)) (sum staged on the fly);
// sel1: h = relu(conv(ev, G1)+g1b); sel2: s1 = relu(conv(ev, S1)).
__global__ __launch_bounds__(256, 3) void conv3x3_l1_blk(
        const unsigned short* __restrict__ evb, const unsigned short* __restrict__ fbb,
        const unsigned short* __restrict__ Wt1g, const unsigned short* __restrict__ G1g,
        const unsigned short* __restrict__ S1g, const float* __restrict__ g1b,
        unsigned short* __restrict__ out_t1, unsigned short* __restrict__ out_h,
        unsigned short* __restrict__ out_s1, const unsigned short* __restrict__ zp) {
    __shared__ unsigned short smIn[20736];
    const int z = blockIdx.z;
    const int b = z & 7, sel = z >> 3;
    const unsigned short* Wg = (sel == 0) ? Wt1g : ((sel == 1) ? G1g : S1g);
    unsigned short* out = (sel == 0) ? out_t1 : ((sel == 1) ? out_h : out_s1);
    const int by = blockIdx.y << 4, bx = blockIdx.x << 4;
    const int tid = threadIdx.x;
    const int lane = tid & 63, w = tid >> 6;
    const int lx = lane & 15, ls = lane >> 4;

    for (int idx = tid; idx < 2592; idx += 256) {
        int oct = idx / 324;
        int p   = idx - oct * 324;
        int yy = p / 18, xx = p - yy * 18;
        int gy = by + yy - 1, gx = bx + xx - 1;
        bool ok = (unsigned)gy < (unsigned)Hn && (unsigned)gx < (unsigned)Wn;
        const size_t off = ((size_t)(b * 8 + oct) * HW + gy * Wn + gx) * 8;
        if (sel == 0) {
            u32x4 v = u32x4{0u, 0u, 0u, 0u};
            if (ok) {
                u32x4 e = *(const u32x4*)(evb + off);
                u32x4 f = *(const u32x4*)(fbb + off);
#pragma unroll
                for (int q = 0; q < 4; ++q)
                    v[q] = (unsigned)f2bf(bfhalf(e[q], 0) + bfhalf(f[q], 0)) |
                           ((unsigned)f2bf(bfhalf(e[q], 1) + bfhalf(f[q], 1)) << 16);
            }
            *(u32x4*)(smIn + idx * 8) = v;
        } else {
            gl_lds16(ok ? evb + off : zp, smIn + idx * 8);
        }
    }
    __syncthreads();

    f32x4 acc[4][4];
#pragma unroll
    for (int m = 0; m < 4; ++m)
#pragma unroll
        for (int n = 0; n < 4; ++n) acc[m][n] = f32x4{0.f, 0.f, 0.f, 0.f};

#pragma unroll
    for (int ky = 0; ky < 3; ++ky)
#pragma unroll
    for (int kx = 0; kx < 3; ++kx) {
        const int t = ky * 3 + kx;
#pragma unroll
        for (int kk = 0; kk < 2; ++kk) {
            bf16x8 a[4];
            const unsigned short* wbase = Wg + kk * 18432 + ls * 4608 + t * 512 + lx * 8;
#pragma unroll
            for (int m = 0; m < 4; ++m)
                a[m] = *(const bf16x8*)(wbase + m * 128);
            const unsigned short* ibase =
                smIn + ((kk * 4 + ls) * 324 + (4 * w + ky) * 18 + lx + kx) * 8;
#pragma unroll
            for (int n = 0; n < 4; ++n) {
                bf16x8 bf = *(const bf16x8*)(ibase + n * 144);
#pragma unroll
                for (int m = 0; m < 4; ++m)
                    acc[m][n] = __builtin_amdgcn_mfma_f32_16x16x32_bf16(
                        a[m], bf, acc[m][n], 0, 0, 0);
            }
        }
    }

    const int y0 = by + 4 * w;
#pragma unroll
    for (int m = 0; m < 4; ++m) {
        float bv[4] = {0.f, 0.f, 0.f, 0.f};
        if (sel == 1) {
            float4 b4 = *(const float4*)(g1b + 16 * m + ls * 4);
            bv[0] = b4.x; bv[1] = b4.y; bv[2] = b4.z; bv[3] = b4.w;
        }
        const size_t rowb = (size_t)(b * 8 + m * 2 + (ls >> 1)) * HW;
        const int j0 = (ls & 1) * 4;
#pragma unroll
        for (int n = 0; n < 4; ++n) {
            const size_t pofs = rowb + (size_t)(y0 + n) * Wn + bx + lx;
            float vr[4];
#pragma unroll
            for (int r = 0; r < 4; ++r)
                vr[r] = fmaxf(acc[m][n][r] + bv[r], 0.f);
            u32x2 pk;
            pk[0] = (unsigned)f2bf(vr[0]) | ((unsigned)f2bf(vr[1]) << 16);
            pk[1] = (unsigned)f2bf(vr[2]) | ((unsigned)f2bf(vr[3]) << 16);
            *(u32x2*)(out + pofs * 8 + j0) = pk;
        }
    }
}

// ---------------- L2: Wt2 conv (store + mean-atomics) + S2 conv (COMP) -------------
__global__ __launch_bounds__(256, 3) void conv3x3_l2_blk(
        const unsigned short* __restrict__ t1, const unsigned short* __restrict__ s1,
        const unsigned short* __restrict__ Wt2g, const unsigned short* __restrict__ S2g,
        unsigned short* __restrict__ out_f, float* __restrict__ comp,
        float* __restrict__ w0, const unsigned short* __restrict__ zp) {
    __shared__ unsigned short smIn[20736];
    const int z = blockIdx.z;
    const int b = z & 7, sel = z >> 3;
    const unsigned short* in = (sel == 0) ? t1 : s1;
    const unsigned short* Wg = (sel == 0) ? Wt2g : S2g;
    const int by = blockIdx.y << 4, bx = blockIdx.x << 4;
    const int tid = threadIdx.x;
    const int lane = tid & 63, w = tid >> 6;
    const int lx = lane & 15, ls = lane >> 4;

    for (int idx = tid; idx < 2592; idx += 256) {
        int oct = idx / 324;
        int p   = idx - oct * 324;
        int yy = p / 18, xx = p - yy * 18;
        int gy = by + yy - 1, gx = bx + xx - 1;
        const unsigned short* src =
            ((unsigned)gy < (unsigned)Hn && (unsigned)gx < (unsigned)Wn)
            ? in + ((size_t)(b * 8 + oct) * HW + gy * Wn + gx) * 8 : zp;
        gl_lds16(src, smIn + idx * 8);
    }
    __syncthreads();

    f32x4 acc[4][4];
#pragma unroll
    for (int m = 0; m < 4; ++m)
#pragma unroll
        for (int n = 0; n < 4; ++n) acc[m][n] = f32x4{0.f, 0.f, 0.f, 0.f};

#pragma unroll
    for (int ky = 0; ky < 3; ++ky)
#pragma unroll
    for (int kx = 0; kx < 3; ++kx) {
        const int t = ky * 3 + kx;
#pragma unroll
        for (int kk = 0; kk < 2; ++kk) {
            bf16x8 a[4];
            const unsigned short* wbase = Wg + kk * 18432 + ls * 4608 + t * 512 + lx * 8;
#pragma unroll
            for (int m = 0; m < 4; ++m)
                a[m] = *(const bf16x8*)(wbase + m * 128);
            const unsigned short* ibase =
                smIn + ((kk * 4 + ls) * 324 + (4 * w + ky) * 18 + lx + kx) * 8;
#pragma unroll
            for (int n = 0; n < 4; ++n) {
                bf16x8 bf = *(const bf16x8*)(ibase + n * 144);
#pragma unroll
                for (int m = 0; m < 4; ++m)
                    acc[m][n] = __builtin_amdgcn_mfma_f32_16x16x32_bf16(
                        a[m], bf, acc[m][n], 0, 0, 0);
            }
        }
    }

    const int y0 = by + 4 * w;
    if (sel == 0) {
#pragma unroll
        for (int m = 0; m < 4; ++m) {
            const size_t rowb = (size_t)(b * 8 + m * 2 + (ls >> 1)) * HW;
            const int j0 = (ls & 1) * 4;
#pragma unroll
            for (int n = 0; n < 4; ++n) {
                const size_t pofs = rowb + (size_t)(y0 + n) * Wn + bx + lx;
                u32x2 pk;
                pk[0] = (unsigned)f2bf(acc[m][n][0]) | ((unsigned)f2bf(acc[m][n][1]) << 16);
                pk[1] = (unsigned)f2bf(acc[m][n][2]) | ((unsigned)f2bf(acc[m][n][3]) << 16);
                *(u32x2*)(out_f + pofs * 8 + j0) = pk;
            }
            // channel-mean partial: reduce over this wave's 16 lx, atomicAdd per co
#pragma unroll
            for (int r = 0; r < 4; ++r) {
                float s = acc[m][0][r] + acc[m][1][r] + acc[m][2][r] + acc[m][3][r];
                s += __shfl_xor(s, 1);
                s += __shfl_xor(s, 2);
                s += __shfl_xor(s, 4);
                s += __shfl_xor(s, 8);
                if (lx == 0)
                    atomicAdd(&w0[b * 64 + 16 * m + ls * 4 + r], s);
            }
        }
    } else {
        float gs[4], gm[4];
#pragma unroll
        for (int n = 0; n < 4; ++n) { gs[n] = 0.f; gm[n] = -1e30f; }
#pragma unroll
        for (int m = 0; m < 4; ++m)
#pragma unroll
            for (int r = 0; r < 4; ++r)
#pragma unroll
                for (int n = 0; n < 4; ++n) {
                    float v = acc[m][n][r];
                    gm[n] = fmaxf(gm[n], v);
                    gs[n] += v;
                }
#pragma unroll
        for (int n = 0; n < 4; ++n) {
            float s = gs[n], mx = gm[n];
            s += __shfl_xor(s, 16);
            s += __shfl_xor(s, 32);
            mx = fmaxf(mx, __shfl_xor(mx, 16));
            mx = fmaxf(mx, __shfl_xor(mx, 32));
            if (ls == 0) {
                const size_t o = (size_t)b * 2 * HW + (size_t)(y0 + n) * Wn + bx + lx;
                comp[o]      = mx;
                comp[o + HW] = s * (1.f / 64.f);
            }
        }
    }
}

// ---------------- merged: rgb-gate conv (z<8) + sconv5 (z>=8) ----------------------
__global__ __launch_bounds__(256, 3) void rgb_sconv_k(
        const unsigned short* __restrict__ in, const unsigned short* __restrict__ Wg,
        const float* __restrict__ gw, const float* __restrict__ gb,
        float* __restrict__ gout,
        const float* __restrict__ comp, const float* __restrict__ Ew,
        const float* __restrict__ eb, float* __restrict__ scale,
        const unsigned short* __restrict__ zp) {
    __shared__ unsigned short smIn[20736];
    const int z = blockIdx.z;
    if (z >= 8) {
        int id = (((z - 8) * 64) + blockIdx.y * 8 + blockIdx.x) * 256 + threadIdx.x;
        int sb = id >> 14, p = id & 16383;
        int y = p >> 7, x = p & 127;
        const float* cb = comp + (size_t)sb * 2 * HW;
        float sacc = eb[0];
#pragma unroll
        for (int ch = 0; ch < 2; ++ch)
#pragma unroll
            for (int ky = 0; ky < 5; ++ky) {
                int gy = y + ky - 2;
                if ((unsigned)gy >= (unsigned)Hn) continue;
#pragma unroll
                for (int kx = 0; kx < 5; ++kx) {
                    int gx = x + kx - 2;
                    if ((unsigned)gx >= (unsigned)Wn) continue;
                    sacc = fmaf(Ew[ch * 25 + ky * 5 + kx], cb[ch * HW + gy * Wn + gx], sacc);
                }
            }
        scale[id] = 1.f / (1.f + expf(-sacc));
        return;
    }
    const int b = z;
    const int by = blockIdx.y << 4, bx = blockIdx.x << 4;
    const int tid = threadIdx.x;
    const int lane = tid & 63, w = tid >> 6;
    const int lx = lane & 15, ls = lane >> 4;

    for (int idx = tid; idx < 2592; idx += 256) {
        int oct = idx / 324;
        int p   = idx - oct * 324;
        int yy = p / 18, xx = p - yy * 18;
        int gy = by + yy - 1, gx = bx + xx - 1;
        const unsigned short* src =
            ((unsigned)gy < (unsigned)Hn && (unsigned)gx < (unsigned)Wn)
            ? in + ((size_t)(b * 8 + oct) * HW + gy * Wn + gx) * 8 : zp;
        gl_lds16(src, smIn + idx * 8);
    }
    __syncthreads();

    f32x4 acc[4][4];
#pragma unroll
    for (int m = 0; m < 4; ++m)
#pragma unroll
        for (int n = 0; n < 4; ++n) acc[m][n] = f32x4{0.f, 0.f, 0.f, 0.f};

#pragma unroll
    for (int ky = 0; ky < 3; ++ky)
#pragma unroll
    for (int kx = 0; kx < 3; ++kx) {
        const int t = ky * 3 + kx;
#pragma unroll
        for (int kk = 0; kk < 2; ++kk) {
            bf16x8 a[4];
            const unsigned short* wbase = Wg + kk * 18432 + ls * 4608 + t * 512 + lx * 8;
#pragma unroll
            for (int m = 0; m < 4; ++m)
                a[m] = *(const bf16x8*)(wbase + m * 128);
            const unsigned short* ibase =
                smIn + ((kk * 4 + ls) * 324 + (4 * w + ky) * 18 + lx + kx) * 8;
#pragma unroll
            for (int n = 0; n < 4; ++n) {
                bf16x8 bf = *(const bf16x8*)(ibase + n * 144);
#pragma unroll
                for (int m = 0; m < 4; ++m)
                    acc[m][n] = __builtin_amdgcn_mfma_f32_16x16x32_bf16(
                        a[m], bf, acc[m][n], 0, 0, 0);
            }
        }
    }

    // epilogue: fused2 = in + relu(conv); rgb = sum_c gw[c]*fused2 + gb
    // residual read from smIn center (oct = m*2+(ls>>1), row 4w+n+1, col lx+1)
    const int y0 = by + 4 * w;
    float gs[4];
#pragma unroll
    for (int n = 0; n < 4; ++n) gs[n] = 0.f;
#pragma unroll
    for (int m = 0; m < 4; ++m) {
        float4 rw4 = *(const float4*)(gw + 16 * m + ls * 4);
        const float rwf[4] = {rw4.x, rw4.y, rw4.z, rw4.w};
        const int oct = m * 2 + (ls >> 1);
        const int j0 = (ls & 1) * 4;
#pragma unroll
        for (int n = 0; n < 4; ++n) {
            u32x2 rin = *(const u32x2*)(smIn +
                (oct * 324 + (4 * w + n + 1) * 18 + lx + 1) * 8 + j0);
#pragma unroll
            for (int r = 0; r < 4; ++r) {
                float v = fmaxf(acc[m][n][r], 0.f) + bfhalf(rin[r >> 1], r & 1);
                gs[n] = fmaf(rwf[r], v, gs[n]);
            }
        }
    }
#pragma unroll
    for (int n = 0; n < 4; ++n) {
        float s = gs[n];
        s += __shfl_xor(s, 16);
        s += __shfl_xor(s, 32);
        if (ls == 0)
            gout[(size_t)b * HW + (size_t)(y0 + n) * Wn + bx + lx] = s + gb[0];
    }
}

// ---------------- SE MLP (w0 holds SUMS; scale by 1/16384 here) ----------------
__global__ void mlp_k(const float* __restrict__ w0, const float* __restrict__ A1,
                      const float* __restrict__ b1, const float* __restrict__ A2,
                      const float* __restrict__ b2, float* __restrict__ w0s) {
    int b = blockIdx.x, t = threadIdx.x;       // 128 threads
    __shared__ float w0r[64], hid[128];
    if (t < 64) w0r[t] = w0[b * 64 + t] * (1.f / 16384.f);
    __syncthreads();
    float s = b1[t];
    for (int c = 0; c < 64; ++c) s = fmaf(A1[t * 64 + c], w0r[c], s);
    hid[t] = fmaxf(s, 0.f);
    __syncthreads();
    if (t < 64) {
        float s2 = b2[t];
        for (int j = 0; j < 128; ++j) s2 = fmaf(A2[t * 128 + j], hid[j], s2);
        w0s[b * 64 + t] = 1.f / (1.f + expf(-s2));
    }
}

// ---------------- fused dynamic conv (transposed swizzled kern [px][rl]) ----------
__global__ __launch_bounds__(256, 4) void dynfused_k(
        const unsigned short* __restrict__ fbb, const unsigned short* __restrict__ hb,
        const unsigned short* __restrict__ G2p, const float* __restrict__ g2b,
        const float* __restrict__ w0s, const float* __restrict__ rgb,
        unsigned short* __restrict__ outb) {
    __shared__ unsigned short smU[8192];       // union: h staging -> kern[px][64 swz] -> out
    __shared__ unsigned short smFB[11520];     // [c64][180] gated patch, 22.5 KB
    const int b  = blockIdx.z;
    const int by = blockIdx.y << 3, bx = blockIdx.x << 4;
    const int tid = threadIdx.x;
    const int lane = tid & 63, w = tid >> 6;
    const int lx = lane & 15, ls = lane >> 4;
    const int wr = w & 1, wc = w >> 1;
    const int px = tid & 127;
    const int chalf = __builtin_amdgcn_readfirstlane(tid >> 7);  // wave-uniform
    const int ty = px >> 4, tx = px & 15;

    // stage h: async direct-to-LDS -> smU [oct][px][8]
#pragma unroll
    for (int it = 0; it < 4; ++it) {
        int i = tid + it * 256;
        int p = i & 127, oct = i >> 7;
        gl_lds16(hb + ((size_t)(b * 8 + oct) * HW + (by + (p >> 4)) * Wn + bx + (p & 15)) * 8,
                 smU + i * 8);
    }
    // stage fb patch with fb1 gating: blocked b128 load, gate, scatter to [c][180]
    const float* rgbb = rgb + (size_t)b * HW;
    for (int i = tid; i < 1440; i += 256) {
        int oct = i / 180, p = i - oct * 180;
        int pr = p / 18, pc = p - pr * 18;
        int gy = min(max(by + pr - 1, 0), Hn - 1);
        int gx = min(max(bx + pc - 1, 0), Wn - 1);
        u32x4 v = *(const u32x4*)(fbb + ((size_t)(b * 8 + oct) * HW + gy * Wn + gx) * 8);
        float g = 1.f + rgbb[gy * Wn + gx];
        float4 s0 = *(const float4*)(w0s + b * 64 + oct * 8);
        float4 s1 = *(const float4*)(w0s + b * 64 + oct * 8 + 4);
        const float sc[8] = {1.f + s0.x, 1.f + s0.y, 1.f + s0.z, 1.f + s0.w,
                             1.f + s1.x, 1.f + s1.y, 1.f + s1.z, 1.f + s1.w};
#pragma unroll
        for (int j = 0; j < 8; ++j)
            smFB[(oct * 8 + j) * 180 + p] = f2bf(bfhalf(v[j >> 1], j & 1) * sc[j] * g);
    }
    __syncthreads();

    // hoist b-frags (chunk-invariant) from smU to registers
    bf16x8 bv[2][4];
#pragma unroll
    for (int kk = 0; kk < 2; ++kk)
#pragma unroll
        for (int n = 0; n < 4; ++n)
            bv[kk][n] = *(const bf16x8*)(smU + ((kk * 4 + ls) * 128 + wc * 64 + n * 16 + lx) * 8);
    __syncthreads();                           // all reads done before smU becomes kern

    float acc[32];
#pragma unroll
    for (int s = 0; s < 32; ++s) acc[s] = 0.f;

#pragma unroll
    for (int chunk = 0; chunk < 9; ++chunk) {
        // GEMM: rows chunk*64 + wr*32 + [0,32), px wc*64 + [0,64), K=64
        f32x4 ka[2][4];
#pragma unroll
        for (int m = 0; m < 2; ++m)
#pragma unroll
            for (int n = 0; n < 4; ++n) ka[m][n] = f32x4{0.f, 0.f, 0.f, 0.f};
#pragma unroll
        for (int kk = 0; kk < 2; ++kk) {
            bf16x8 a[2];
#pragma unroll
            for (int m = 0; m < 2; ++m)
                a[m] = *(const bf16x8*)(G2p +
                        (size_t)(chunk * 64 + wr * 32 + m * 16 + lx) * 64 + kk * 32 + ls * 8);
#pragma unroll
            for (int n = 0; n < 4; ++n)
#pragma unroll
                for (int m = 0; m < 2; ++m)
                    ka[m][n] = __builtin_amdgcn_mfma_f32_16x16x32_bf16(a[m], bv[kk][n], ka[m][n], 0, 0, 0);
        }
        // epilogue: + g2b, write kern TRANSPOSED [pxl][rl] with 16B-granule XOR swizzle
#pragma unroll
        for (int m = 0; m < 2; ++m) {
            const float4 bb4 = *(const float4*)(g2b + chunk * 64 + wr * 32 + m * 16 + ls * 4);
            const float bb[4] = {bb4.x, bb4.y, bb4.z, bb4.w};
            const int rl0 = wr * 32 + m * 16 + ls * 4;   // multiple of 4
            const int gr = rl0 >> 3, sub = rl0 & 7;      // sub in {0,4}
#pragma unroll
            for (int n = 0; n < 4; ++n) {
                const int pxl = wc * 64 + n * 16 + lx;
                u32x2 pk;
                pk[0] = (unsigned)f2bf(ka[m][n][0] + bb[0]) |
                        ((unsigned)f2bf(ka[m][n][1] + bb[1]) << 16);
                pk[1] = (unsigned)f2bf(ka[m][n][2] + bb[2]) |
                        ((unsigned)f2bf(ka[m][n][3] + bb[3]) << 16);
                *(u32x2*)(smU + pxl * 64 + ((gr ^ (pxl & 7)) << 3) + sub) = pk;
            }
        }
        __syncthreads();
        // load own px column: all 64 rows as 8 b128
        u32x4 kvr[8];
#pragma unroll
        for (int k = 0; k < 8; ++k)
            kvr[k] = *(const u32x4*)(smU + px * 64 + ((k ^ (px & 7)) << 3));
        // apply: rows of this chunk whose channel parity == chalf (c,t compile-time)
#pragma unroll
        for (int rl = 0; rl < 64; ++rl) {
            const int r = chunk * 64 + rl;         // compile-time
            const int c = r / 9, t = r - c * 9;    // compile-time
            const int s = c >> 1;
            if ((c & 1) == chalf) {
                float kv = bfhalf(kvr[rl >> 3][(rl & 7) >> 1], rl & 1);
                float pv = bf2f(smFB[c * 180 + (ty + t / 3) * 18 + tx + (t % 3)]);
                acc[s] = fmaf(kv, pv, acc[s]);
            }
        }
        __syncthreads();                       // apply reads done before next epilogue
    }

    // out = fb1 (gated center) + dynconv; transpose through smU -> blocked b128
#pragma unroll
    for (int s = 0; s < 32; ++s) {
        const int c = 2 * s + chalf;
        float res = bf2f(smFB[c * 180 + (ty + 1) * 18 + (tx + 1)]);
        smU[c * 128 + px] = f2bf(acc[s] + res);
    }
    __syncthreads();
#pragma unroll
    for (int it = 0; it < 4; ++it) {
        int i = tid + it * 256;
        int p = i & 127, oct = i >> 7;
        u32x4 pk;
#pragma unroll
        for (int q = 0; q < 4; ++q)
            pk[q] = (unsigned)smU[(oct * 8 + 2 * q) * 128 + p] |
                    ((unsigned)smU[(oct * 8 + 2 * q + 1) * 128 + p] << 16);
        *(u32x4*)(outb + ((size_t)(b * 8 + oct) * HW + (by + (p >> 4)) * Wn + bx + (p & 15)) * 8) = pk;
    }
}

// ---------------- final fusion via MFMA: out = Fw @ concat(ev*(1+sc), fb2) -----
__global__ __launch_bounds__(256, 3) void fuse_mfma_k(
        const unsigned short* __restrict__ evb, const float* __restrict__ scale,
        const unsigned short* __restrict__ fb2b, const unsigned short* __restrict__ Fwp,
        float* __restrict__ out) {
    __shared__ unsigned short smF[16384];   // [oct16][px128][8ci] 32 KB
    const int bid = blockIdx.x;
    const int b = bid >> 7, px0 = (bid & 127) << 7;
    const int tid = threadIdx.x;
    const int lane = tid & 63, w = tid >> 6;
    const int lx = lane & 15, ls = lane >> 4;
    const int wr = w & 1, wc = w >> 1;
    const float* sc = scale + b * HW + px0;

    // fb2 half: async direct-to-LDS (issue first so it overlaps the ev compute)
#pragma unroll
    for (int it = 4; it < 8; ++it) {
        int slot = tid + it * 256;
        int oct = slot >> 7, pxl = slot & 127;
        gl_lds16(fb2b + ((size_t)(b * 8 + oct - 8) * HW + px0 + pxl) * 8, smF + slot * 8);
    }
    // ev half: scaled through registers
#pragma unroll
    for (int it = 0; it < 4; ++it) {
        int slot = tid + it * 256;
        int oct = slot >> 7, pxl = slot & 127;
        u32x4 v = *(const u32x4*)(evb + ((size_t)(b * 8 + oct) * HW + px0 + pxl) * 8);
        float s = 1.f + sc[pxl];
#pragma unroll
        for (int q = 0; q < 4; ++q)
            v[q] = (unsigned)f2bf(bfhalf(v[q], 0) * s) |
                   ((unsigned)f2bf(bfhalf(v[q], 1) * s) << 16);
        ((u32x4*)smF)[slot] = v;
    }
    __syncthreads();

    f32x4 acc[4][4];
#pragma unroll
    for (int m = 0; m < 4; ++m)
#pragma unroll
        for (int n = 0; n < 4; ++n) acc[m][n] = f32x4{0.f, 0.f, 0.f, 0.f};

#pragma unroll
    for (int kk = 0; kk < 4; ++kk) {
        bf16x8 a[4];
#pragma unroll
        for (int m = 0; m < 4; ++m)
            a[m] = *(const bf16x8*)(Fwp + (size_t)(wr * 64 + m * 16 + lx) * 128 + kk * 32 + ls * 8);
#pragma unroll
        for (int n = 0; n < 4; ++n) {
            bf16x8 bv = *(const bf16x8*)(smF + ((kk * 4 + ls) * 128 + wc * 64 + n * 16 + lx) * 8);
#pragma unroll
            for (int m = 0; m < 4; ++m)
                acc[m][n] = __builtin_amdgcn_mfma_f32_16x16x32_bf16(a[m], bv, acc[m][n], 0, 0, 0);
        }
    }

    const size_t ob = (size_t)b * 2 * CHW + px0 + wc * 64;
#pragma unroll
    for (int m = 0; m < 4; ++m)
#pragma unroll
        for (int n = 0; n < 4; ++n)
#pragma unroll
            for (int j = 0; j < 4; ++j) {
                const int co = wr * 64 + m * 16 + ls * 4 + j;
                out[ob + (size_t)co * HW + n * 16 + lx] = acc[m][n][j];
            }
}

// ---------------- host launch ----------------
extern "C" void kernel_launch(void* const* d_in, const int* in_sizes, int n_in,
                              void* d_out, int out_size, void* d_ws, size_t ws_size,
                              hipStream_t stream) {
    const float* f_event = (const float*)d_in[0];
    const float* f_blur  = (const float*)d_in[1];
    const float* Wt1 = (const float*)d_in[2];
    const float* Wt2 = (const float*)d_in[3];
    const float* Wt3 = (const float*)d_in[4];
    const float* A1  = (const float*)d_in[5];
    const float* b1  = (const float*)d_in[6];
    const float* A2  = (const float*)d_in[7];
    const float* b2  = (const float*)d_in[8];
    const float* G1  = (const float*)d_in[9];
    const float* g1b = (const float*)d_in[10];
    const float* G2  = (const float*)d_in[11];
    const float* g2b = (const float*)d_in[12];
    const float* Rw  = (const float*)d_in[13];
    const float* rb  = (const float*)d_in[14];
    const float* S1  = (const float*)d_in[15];
    const float* S2  = (const float*)d_in[16];
    const float* Ew  = (const float*)d_in[17];
    const float* eb  = (const float*)d_in[18];
    const float* Fw  = (const float*)d_in[19];
    float* out = (float*)d_out;

    float* ws    = (float*)d_ws;
    float* w0    = ws;                         // 512 (atomic accumulator)
    float* w0s   = w0 + 512;                   // 512
    float* rgb   = w0s + 512;                  // 131072
    float* comp  = rgb + Bn * HW;              // 262144
    float* scale = comp + 2 * Bn * HW;         // 131072
    unsigned short* wprep = (unsigned short*)(scale + Bn * HW);  // 6 x 36864
    unsigned short* G2p = wprep + 6 * 36864;                     // 36864
    unsigned short* Fwp = G2p + 36864;                           // 16384
    unsigned short* zpad = Fwp + 16384;        // 64 shorts (zero page)
    unsigned short* B0 = zpad + 64;            // evblk
    unsigned short* B2 = B0 + NB;              // t1blk
    unsigned short* B3 = B2 + NB;              // fusedblk -> fb2blk
    unsigned short* B4 = B3 + NB;              // hblk
    unsigned short* B5 = B4 + NB;              // fbblk (blocked f_blur)
    unsigned short* B6 = B5 + NB;              // s1blk

    // 0. weight preps + input blocking (prep2 also zeroes zpad + w0 accumulator)
    prep_w_k<<<dim3(144, 6), 256, 0, stream>>>(Wt1, Wt2, Wt3, G1, S1, S2, wprep);
    prep2_k<<<208, 256, 0, stream>>>(G2, Fw, G2p, Fwp, zpad, w0);
    pre_blk_k<<<4096, 256, 0, stream>>>(f_event, f_blur, B0, B5);
    // 1. L1: t1 = relu(conv(ev+fb,Wt1)); h = relu(conv(ev,G1)+g1b); s1 = relu(conv(ev,S1))
    conv3x3_l1_blk<<<dim3(8, 8, 24), 256, 0, stream>>>(
        B0, B5, wprep + 0 * 36864, wprep + 3 * 36864, wprep + 4 * 36864, g1b,
        B2, B4, B6, zpad);
    // 2. L2: fused = conv(t1, Wt2) (+mean atomics); comp = chan-max/mean(conv(s1, S2))
    conv3x3_l2_blk<<<dim3(8, 8, 16), 256, 0, stream>>>(
        B2, B6, wprep + 1 * 36864, wprep + 5 * 36864, B3, comp, w0, zpad);
    // 3. SE MLP (reads summed w0)
    mlp_k<<<Bn, 128, 0, stream>>>(w0, A1, b1, A2, b2, w0s);
    // 4. merged: rgb gate conv (z<8, residual from LDS) + scale_e sconv5 (z>=8)
    rgb_sconv_k<<<dim3(8, 8, 16), 256, 0, stream>>>(
        B3, wprep + 2 * 36864, Rw, rb, rgb, comp, Ew, eb, scale, zpad);
    // 5. fb2 = fb1 + dynconv(fb1, kern(h)), fb1 gating fused into staging
    dynfused_k<<<dim3(8, 16, Bn), 256, 0, stream>>>(B5, B4, G2p, g2b, w0s, rgb, B3);
    // 6. out = Fw @ concat(ev*(1+scale_e), fb2)
    fuse_mfma_k<<<Bn * HW / 128, 256, 0, stream>>>(B0, scale, B3, Fwp, out);
}

// Round 16
// 219.816 us; speedup vs baseline: 1.0568x; 1.0568x over previous
//
#include <hip/hip_runtime.h>
#include <math.h>

constexpr int Bn = 8, Cn = 64, Hn = 128, Wn = 128;
constexpr int HW  = Hn * Wn;      // 16384
constexpr int CHW = Cn * HW;      // 1048576
constexpr size_t NB = (size_t)Bn * CHW;   // elems per blocked tensor

typedef float  f32x4  __attribute__((ext_vector_type(4)));
typedef __bf16 bf16x8 __attribute__((ext_vector_type(8)));
typedef unsigned int u32x4 __attribute__((ext_vector_type(4)));
typedef unsigned int u32x2 __attribute__((ext_vector_type(2)));

static __device__ __forceinline__ unsigned short f2bf(float f) {
    unsigned u = __builtin_bit_cast(unsigned, f);
    u = (u + 0x7FFF + ((u >> 16) & 1)) >> 16;
    return (unsigned short)u;
}
static __device__ __forceinline__ float bf2f(unsigned short v) {
    unsigned u = (unsigned)v << 16;
    return __builtin_bit_cast(float, u);
}
static __device__ __forceinline__ float bfhalf(unsigned u, int hi) {
    unsigned r = hi ? (u & 0xffff0000u) : (u << 16);
    return __builtin_bit_cast(float, r);
}

// async global->LDS 16B (direct-to-shared); falls back to reg copy if unavailable
static __device__ __forceinline__ void gl_lds16(const unsigned short* g, unsigned short* l) {
#if defined(__has_builtin) && __has_builtin(__builtin_amdgcn_global_load_lds)
    __builtin_amdgcn_global_load_lds(
        (const __attribute__((address_space(1))) void*)g,
        (__attribute__((address_space(3))) void*)l, 16, 0, 0);
#else
    *(u32x4*)l = *(const u32x4*)g;
#endif
}

// ---------------- weight prep: OIHW fp32 -> [kk][s][t][co][8cj] bf16 ----------------
__global__ void prep_w_k(const float* __restrict__ W0, const float* __restrict__ W1,
                         const float* __restrict__ W2, const float* __restrict__ W3,
                         const float* __restrict__ W4, const float* __restrict__ W5,
                         unsigned short* __restrict__ dst) {
    int i = blockIdx.x * 256 + threadIdx.x;
    if (i >= 36864) return;
    const float* W = W0;
    switch (blockIdx.y) {
        case 1: W = W1; break; case 2: W = W2; break;
        case 3: W = W3; break; case 4: W = W4; break; case 5: W = W5; break;
        default: break;
    }
    int cj = i & 7;
    int rest = i >> 3;
    int co = rest & 63;
    rest >>= 6;              // (kk*4+s)*9 + t
    int t  = rest % 9;
    int hs = rest / 9;       // 0..7
    int ci = hs * 8 + cj;
    dst[(size_t)blockIdx.y * 36864 + i] = f2bf(W[(co * 64 + ci) * 9 + t]);
}

// ---------------- prep2: G2/Fw -> bf16; zero-page init ----------------
__global__ void prep2_k(const float* __restrict__ G2, const float* __restrict__ Fw,
                        unsigned short* __restrict__ G2p, unsigned short* __restrict__ Fwp,
                        unsigned short* __restrict__ zp) {
    int i = blockIdx.x * 256 + threadIdx.x;
    if (i < 64) zp[i] = 0;
    if (i < 36864) G2p[i] = f2bf(G2[i]);
    else if (i < 36864 + 16384) Fwp[i - 36864] = f2bf(Fw[i - 36864]);
}

// ---------------- pre: blocked bf16 of f_event, f_event+f_blur, f_blur ----------
__global__ void pre_blk_k(const float* __restrict__ fe, const float* __restrict__ fb,
                          unsigned short* __restrict__ evb, unsigned short* __restrict__ f0b,
                          unsigned short* __restrict__ fbb) {
    int i = blockIdx.x * 256 + threadIdx.x;       // (b, oct, px)
    int px = i & 16383;
    int oct = (i >> 14) & 7;
    int b = i >> 17;
    const float* pe = fe + (size_t)b * CHW + (size_t)oct * 8 * HW + px;
    const float* pb = fb + (size_t)b * CHW + (size_t)oct * 8 * HW + px;
    u32x4 ev, f0, fbv;
#pragma unroll
    for (int q = 0; q < 4; ++q) {
        float e0 = pe[(size_t)(2 * q) * HW],     b0 = pb[(size_t)(2 * q) * HW];
        float e1 = pe[(size_t)(2 * q + 1) * HW], b1 = pb[(size_t)(2 * q + 1) * HW];
        ev[q]  = (unsigned)f2bf(e0) | ((unsigned)f2bf(e1) << 16);
        f0[q]  = (unsigned)f2bf(e0 + b0) | ((unsigned)f2bf(e1 + b1) << 16);
        fbv[q] = (unsigned)f2bf(b0) | ((unsigned)f2bf(b1) << 16);
    }
    const size_t o = ((size_t)(b * 8 + oct) * HW + px) * 8;
    *(u32x4*)(evb + o) = ev;
    *(u32x4*)(f0b + o) = f0;
    *(u32x4*)(fbb + o) = fbv;
}

// ---------------- L1: three independent RELU convs in one launch -------------------
__global__ __launch_bounds__(256, 3) void conv3x3_l1_blk(
        const unsigned short* __restrict__ f0, const unsigned short* __restrict__ ev,
        const unsigned short* __restrict__ Wt1g, const unsigned short* __restrict__ G1g,
        const unsigned short* __restrict__ S1g, const float* __restrict__ g1b,
        unsigned short* __restrict__ out_t1, unsigned short* __restrict__ out_h,
        unsigned short* __restrict__ out_s1, const unsigned short* __restrict__ zp) {
    __shared__ unsigned short smIn[20736];
    const int z = blockIdx.z;
    const int b = z & 7, sel = z >> 3;
    const unsigned short* in = (sel == 0) ? f0 : ev;
    const unsigned short* Wg = (sel == 0) ? Wt1g : ((sel == 1) ? G1g : S1g);
    unsigned short* out = (sel == 0) ? out_t1 : ((sel == 1) ? out_h : out_s1);
    const int by = blockIdx.y << 4, bx = blockIdx.x << 4;
    const int tid = threadIdx.x;
    const int lane = tid & 63, w = tid >> 6;
    const int lx = lane & 15, ls = lane >> 4;

    for (int idx = tid; idx < 2592; idx += 256) {
        int oct = idx / 324;
        int p   = idx - oct * 324;
        int yy = p / 18, xx = p - yy * 18;
        int gy = by + yy - 1, gx = bx + xx - 1;
        const unsigned short* src =
            ((unsigned)gy < (unsigned)Hn && (unsigned)gx < (unsigned)Wn)
            ? in + ((size_t)(b * 8 + oct) * HW + gy * Wn + gx) * 8 : zp;
        gl_lds16(src, smIn + idx * 8);
    }
    __syncthreads();

    f32x4 acc[4][4];
#pragma unroll
    for (int m = 0; m < 4; ++m)
#pragma unroll
        for (int n = 0; n < 4; ++n) acc[m][n] = f32x4{0.f, 0.f, 0.f, 0.f};

#pragma unroll
    for (int ky = 0; ky < 3; ++ky)
#pragma unroll
    for (int kx = 0; kx < 3; ++kx) {
        const int t = ky * 3 + kx;
#pragma unroll
        for (int kk = 0; kk < 2; ++kk) {
            bf16x8 a[4];
            const unsigned short* wbase = Wg + kk * 18432 + ls * 4608 + t * 512 + lx * 8;
#pragma unroll
            for (int m = 0; m < 4; ++m)
                a[m] = *(const bf16x8*)(wbase + m * 128);
            const unsigned short* ibase =
                smIn + ((kk * 4 + ls) * 324 + (4 * w + ky) * 18 + lx + kx) * 8;
#pragma unroll
            for (int n = 0; n < 4; ++n) {
                bf16x8 bf = *(const bf16x8*)(ibase + n * 144);
#pragma unroll
                for (int m = 0; m < 4; ++m)
                    acc[m][n] = __builtin_amdgcn_mfma_f32_16x16x32_bf16(
                        a[m], bf, acc[m][n], 0, 0, 0);
            }
        }
    }

    const int y0 = by + 4 * w;
#pragma unroll
    for (int m = 0; m < 4; ++m) {
        float bv[4] = {0.f, 0.f, 0.f, 0.f};
        if (sel == 1) {
            float4 b4 = *(const float4*)(g1b + 16 * m + ls * 4);
            bv[0] = b4.x; bv[1] = b4.y; bv[2] = b4.z; bv[3] = b4.w;
        }
        const size_t rowb = (size_t)(b * 8 + m * 2 + (ls >> 1)) * HW;
        const int j0 = (ls & 1) * 4;
#pragma unroll
        for (int n = 0; n < 4; ++n) {
            const size_t pofs = rowb + (size_t)(y0 + n) * Wn + bx + lx;
            float vr[4];
#pragma unroll
            for (int r = 0; r < 4; ++r)
                vr[r] = fmaxf(acc[m][n][r] + bv[r], 0.f);
            u32x2 pk;
            pk[0] = (unsigned)f2bf(vr[0]) | ((unsigned)f2bf(vr[1]) << 16);
            pk[1] = (unsigned)f2bf(vr[2]) | ((unsigned)f2bf(vr[3]) << 16);
            *(u32x2*)(out + pofs * 8 + j0) = pk;
        }
    }
}

// ---------------- L2: Wt2 conv (store) + S2 conv (COMP epilogue) -------------------
__global__ __launch_bounds__(256, 3) void conv3x3_l2_blk(
        const unsigned short* __restrict__ t1, const unsigned short* __restrict__ s1,
        const unsigned short* __restrict__ Wt2g, const unsigned short* __restrict__ S2g,
        unsigned short* __restrict__ out_f, float* __restrict__ comp,
        const unsigned short* __restrict__ zp) {
    __shared__ unsigned short smIn[20736];
    const int z = blockIdx.z;
    const int b = z & 7, sel = z >> 3;
    const unsigned short* in = (sel == 0) ? t1 : s1;
    const unsigned short* Wg = (sel == 0) ? Wt2g : S2g;
    const int by = blockIdx.y << 4, bx = blockIdx.x << 4;
    const int tid = threadIdx.x;
    const int lane = tid & 63, w = tid >> 6;
    const int lx = lane & 15, ls = lane >> 4;

    for (int idx = tid; idx < 2592; idx += 256) {
        int oct = idx / 324;
        int p   = idx - oct * 324;
        int yy = p / 18, xx = p - yy * 18;
        int gy = by + yy - 1, gx = bx + xx - 1;
        const unsigned short* src =
            ((unsigned)gy < (unsigned)Hn && (unsigned)gx < (unsigned)Wn)
            ? in + ((size_t)(b * 8 + oct) * HW + gy * Wn + gx) * 8 : zp;
        gl_lds16(src, smIn + idx * 8);
    }
    __syncthreads();

    f32x4 acc[4][4];
#pragma unroll
    for (int m = 0; m < 4; ++m)
#pragma unroll
        for (int n = 0; n < 4; ++n) acc[m][n] = f32x4{0.f, 0.f, 0.f, 0.f};

#pragma unroll
    for (int ky = 0; ky < 3; ++ky)
#pragma unroll
    for (int kx = 0; kx < 3; ++kx) {
        const int t = ky * 3 + kx;
#pragma unroll
        for (int kk = 0; kk < 2; ++kk) {
            bf16x8 a[4];
            const unsigned short* wbase = Wg + kk * 18432 + ls * 4608 + t * 512 + lx * 8;
#pragma unroll
            for (int m = 0; m < 4; ++m)
                a[m] = *(const bf16x8*)(wbase + m * 128);
            const unsigned short* ibase =
                smIn + ((kk * 4 + ls) * 324 + (4 * w + ky) * 18 + lx + kx) * 8;
#pragma unroll
            for (int n = 0; n < 4; ++n) {
                bf16x8 bf = *(const bf16x8*)(ibase + n * 144);
#pragma unroll
                for (int m = 0; m < 4; ++m)
                    acc[m][n] = __builtin_amdgcn_mfma_f32_16x16x32_bf16(
                        a[m], bf, acc[m][n], 0, 0, 0);
            }
        }
    }

    const int y0 = by + 4 * w;
    if (sel == 0) {
#pragma unroll
        for (int m = 0; m < 4; ++m) {
            const size_t rowb = (size_t)(b * 8 + m * 2 + (ls >> 1)) * HW;
            const int j0 = (ls & 1) * 4;
#pragma unroll
            for (int n = 0; n < 4; ++n) {
                const size_t pofs = rowb + (size_t)(y0 + n) * Wn + bx + lx;
                u32x2 pk;
                pk[0] = (unsigned)f2bf(acc[m][n][0]) | ((unsigned)f2bf(acc[m][n][1]) << 16);
                pk[1] = (unsigned)f2bf(acc[m][n][2]) | ((unsigned)f2bf(acc[m][n][3]) << 16);
                *(u32x2*)(out_f + pofs * 8 + j0) = pk;
            }
        }
    } else {
        float gs[4], gm[4];
#pragma unroll
        for (int n = 0; n < 4; ++n) { gs[n] = 0.f; gm[n] = -1e30f; }
#pragma unroll
        for (int m = 0; m < 4; ++m)
#pragma unroll
            for (int r = 0; r < 4; ++r)
#pragma unroll
                for (int n = 0; n < 4; ++n) {
                    float v = acc[m][n][r];
                    gm[n] = fmaxf(gm[n], v);
                    gs[n] += v;
                }
#pragma unroll
        for (int n = 0; n < 4; ++n) {
            float s = gs[n], mx = gm[n];
            s += __shfl_xor(s, 16);
            s += __shfl_xor(s, 32);
            mx = fmaxf(mx, __shfl_xor(mx, 16));
            mx = fmaxf(mx, __shfl_xor(mx, 32));
            if (ls == 0) {
                const size_t o = (size_t)b * 2 * HW + (size_t)(y0 + n) * Wn + bx + lx;
                comp[o]      = mx;
                comp[o + HW] = s * (1.f / 64.f);
            }
        }
    }
}

// ---------------- merged: rgb-gate conv (z<8) + sconv5 (z>=8) ----------------------
__global__ __launch_bounds__(256, 3) void rgb_sconv_k(
        const unsigned short* __restrict__ in, const unsigned short* __restrict__ Wg,
        const float* __restrict__ gw, const float* __restrict__ gb,
        float* __restrict__ gout,
        const float* __restrict__ comp, const float* __restrict__ Ew,
        const float* __restrict__ eb, float* __restrict__ scale,
        const unsigned short* __restrict__ zp) {
    __shared__ unsigned short smIn[20736];
    const int z = blockIdx.z;
    if (z >= 8) {
        // sconv5: linear block (z-8)*64 + by*8 + bx
        int id = (((z - 8) * 64) + blockIdx.y * 8 + blockIdx.x) * 256 + threadIdx.x;
        int sb = id >> 14, p = id & 16383;
        int y = p >> 7, x = p & 127;
        const float* cb = comp + (size_t)sb * 2 * HW;
        float sacc = eb[0];
#pragma unroll
        for (int ch = 0; ch < 2; ++ch)
#pragma unroll
            for (int ky = 0; ky < 5; ++ky) {
                int gy = y + ky - 2;
                if ((unsigned)gy >= (unsigned)Hn) continue;
#pragma unroll
                for (int kx = 0; kx < 5; ++kx) {
                    int gx = x + kx - 2;
                    if ((unsigned)gx >= (unsigned)Wn) continue;
                    sacc = fmaf(Ew[ch * 25 + ky * 5 + kx], cb[ch * HW + gy * Wn + gx], sacc);
                }
            }
        scale[id] = 1.f / (1.f + expf(-sacc));
        return;
    }
    const int b = z;
    const int by = blockIdx.y << 4, bx = blockIdx.x << 4;
    const int tid = threadIdx.x;
    const int lane = tid & 63, w = tid >> 6;
    const int lx = lane & 15, ls = lane >> 4;

    for (int idx = tid; idx < 2592; idx += 256) {
        int oct = idx / 324;
        int p   = idx - oct * 324;
        int yy = p / 18, xx = p - yy * 18;
        int gy = by + yy - 1, gx = bx + xx - 1;
        const unsigned short* src =
            ((unsigned)gy < (unsigned)Hn && (unsigned)gx < (unsigned)Wn)
            ? in + ((size_t)(b * 8 + oct) * HW + gy * Wn + gx) * 8 : zp;
        gl_lds16(src, smIn + idx * 8);
    }
    __syncthreads();

    f32x4 acc[4][4];
#pragma unroll
    for (int m = 0; m < 4; ++m)
#pragma unroll
        for (int n = 0; n < 4; ++n) acc[m][n] = f32x4{0.f, 0.f, 0.f, 0.f};

#pragma unroll
    for (int ky = 0; ky < 3; ++ky)
#pragma unroll
    for (int kx = 0; kx < 3; ++kx) {
        const int t = ky * 3 + kx;
#pragma unroll
        for (int kk = 0; kk < 2; ++kk) {
            bf16x8 a[4];
            const unsigned short* wbase = Wg + kk * 18432 + ls * 4608 + t * 512 + lx * 8;
#pragma unroll
            for (int m = 0; m < 4; ++m)
                a[m] = *(const bf16x8*)(wbase + m * 128);
            const unsigned short* ibase =
                smIn + ((kk * 4 + ls) * 324 + (4 * w + ky) * 18 + lx + kx) * 8;
#pragma unroll
            for (int n = 0; n < 4; ++n) {
                bf16x8 bf = *(const bf16x8*)(ibase + n * 144);
#pragma unroll
                for (int m = 0; m < 4; ++m)
                    acc[m][n] = __builtin_amdgcn_mfma_f32_16x16x32_bf16(
                        a[m], bf, acc[m][n], 0, 0, 0);
            }
        }
    }

    // epilogue: fused2 = in + relu(conv); rgb = sum_c gw[c]*fused2 + gb
    const int y0 = by + 4 * w;
    float gs[4];
#pragma unroll
    for (int n = 0; n < 4; ++n) gs[n] = 0.f;
#pragma unroll
    for (int m = 0; m < 4; ++m) {
        float4 rw4 = *(const float4*)(gw + 16 * m + ls * 4);
        const float rwf[4] = {rw4.x, rw4.y, rw4.z, rw4.w};
        const size_t rowb = (size_t)(b * 8 + m * 2 + (ls >> 1)) * HW;
        const int j0 = (ls & 1) * 4;
#pragma unroll
        for (int n = 0; n < 4; ++n) {
            const size_t pofs = rowb + (size_t)(y0 + n) * Wn + bx + lx;
            u32x2 rin = *(const u32x2*)(in + pofs * 8 + j0);
#pragma unroll
            for (int r = 0; r < 4; ++r) {
                float v = fmaxf(acc[m][n][r], 0.f) + bfhalf(rin[r >> 1], r & 1);
                gs[n] = fmaf(rwf[r], v, gs[n]);
            }
        }
    }
#pragma unroll
    for (int n = 0; n < 4; ++n) {
        float s = gs[n];
        s += __shfl_xor(s, 16);
        s += __shfl_xor(s, 32);
        if (ls == 0)
            gout[(size_t)b * HW + (size_t)(y0 + n) * Wn + bx + lx] = s + gb[0];
    }
}

// ---------------- mean over H,W per (b,oct) from blocked bf16 ----------------
__global__ void mean_hw_blk(const unsigned short* __restrict__ in, float* __restrict__ w0) {
    __shared__ float red[256][8];
    const int bo = blockIdx.x;                 // b*8+oct
    const int tid = threadIdx.x;
    const unsigned short* p = in + (size_t)bo * HW * 8;
    float s[8];
#pragma unroll
    for (int j = 0; j < 8; ++j) s[j] = 0.f;
    for (int it = 0; it < 64; ++it) {
        u32x4 v = *(const u32x4*)(p + (size_t)(tid + it * 256) * 8);
#pragma unroll
        for (int j = 0; j < 8; ++j) s[j] += bfhalf(v[j >> 1], j & 1);
    }
#pragma unroll
    for (int j = 0; j < 8; ++j) red[tid][j] = s[j];
    __syncthreads();
    for (int off = 128; off > 0; off >>= 1) {
        if (tid < off)
#pragma unroll
            for (int j = 0; j < 8; ++j) red[tid][j] += red[tid + off][j];
        __syncthreads();
    }
    if (tid < 8) w0[bo * 8 + tid] = red[0][tid] * (1.f / 16384.f);
}

// ---------------- SE MLP ----------------
__global__ void mlp_k(const float* __restrict__ w0, const float* __restrict__ A1,
                      const float* __restrict__ b1, const float* __restrict__ A2,
                      const float* __restrict__ b2, float* __restrict__ w0s) {
    int b = blockIdx.x, t = threadIdx.x;       // 128 threads
    __shared__ float w0r[64], hid[128];
    if (t < 64) w0r[t] = w0[b * 64 + t];
    __syncthreads();
    float s = b1[t];
    for (int c = 0; c < 64; ++c) s = fmaf(A1[t * 64 + c], w0r[c], s);
    hid[t] = fmaxf(s, 0.f);
    __syncthreads();
    if (t < 64) {
        float s2 = b2[t];
        for (int j = 0; j < 128; ++j) s2 = fmaf(A2[t * 128 + j], hid[j], s2);
        w0s[b * 64 + t] = 1.f / (1.f + expf(-s2));
    }
}

// ---------------- fused dynamic conv (transposed swizzled kern [px][rl]) ----------
__global__ __launch_bounds__(256, 4) void dynfused_k(
        const unsigned short* __restrict__ fbb, const unsigned short* __restrict__ hb,
        const unsigned short* __restrict__ G2p, const float* __restrict__ g2b,
        const float* __restrict__ w0s, const float* __restrict__ rgb,
        unsigned short* __restrict__ outb) {
    __shared__ unsigned short smU[8192];       // union: h staging -> kern[px][64 swz] -> out
    __shared__ unsigned short smFB[11520];     // [c64][180] gated patch, 22.5 KB
    const int b  = blockIdx.z;
    const int by = blockIdx.y << 3, bx = blockIdx.x << 4;
    const int tid = threadIdx.x;
    const int lane = tid & 63, w = tid >> 6;
    const int lx = lane & 15, ls = lane >> 4;
    const int wr = w & 1, wc = w >> 1;
    const int px = tid & 127;
    const int chalf = __builtin_amdgcn_readfirstlane(tid >> 7);  // wave-uniform
    const int ty = px >> 4, tx = px & 15;

    // stage h: async direct-to-LDS -> smU [oct][px][8]
#pragma unroll
    for (int it = 0; it < 4; ++it) {
        int i = tid + it * 256;
        int p = i & 127, oct = i >> 7;
        gl_lds16(hb + ((size_t)(b * 8 + oct) * HW + (by + (p >> 4)) * Wn + bx + (p & 15)) * 8,
                 smU + i * 8);
    }
    // stage fb patch with fb1 gating: blocked b128 load, gate, scatter to [c][180]
    const float* rgbb = rgb + (size_t)b * HW;
    for (int i = tid; i < 1440; i += 256) {
        int oct = i / 180, p = i - oct * 180;
        int pr = p / 18, pc = p - pr * 18;
        int gy = min(max(by + pr - 1, 0), Hn - 1);
        int gx = min(max(bx + pc - 1, 0), Wn - 1);
        u32x4 v = *(const u32x4*)(fbb + ((size_t)(b * 8 + oct) * HW + gy * Wn + gx) * 8);
        float g = 1.f + rgbb[gy * Wn + gx];
        float4 s0 = *(const float4*)(w0s + b * 64 + oct * 8);
        float4 s1 = *(const float4*)(w0s + b * 64 + oct * 8 + 4);
        const float sc[8] = {1.f + s0.x, 1.f + s0.y, 1.f + s0.z, 1.f + s0.w,
                             1.f + s1.x, 1.f + s1.y, 1.f + s1.z, 1.f + s1.w};
#pragma unroll
        for (int j = 0; j < 8; ++j)
            smFB[(oct * 8 + j) * 180 + p] = f2bf(bfhalf(v[j >> 1], j & 1) * sc[j] * g);
    }
    __syncthreads();

    // hoist b-frags (chunk-invariant) from smU to registers
    bf16x8 bv[2][4];
#pragma unroll
    for (int kk = 0; kk < 2; ++kk)
#pragma unroll
        for (int n = 0; n < 4; ++n)
            bv[kk][n] = *(const bf16x8*)(smU + ((kk * 4 + ls) * 128 + wc * 64 + n * 16 + lx) * 8);
    __syncthreads();                           // all reads done before smU becomes kern

    float acc[32];
#pragma unroll
    for (int s = 0; s < 32; ++s) acc[s] = 0.f;

#pragma unroll
    for (int chunk = 0; chunk < 9; ++chunk) {
        // GEMM: rows chunk*64 + wr*32 + [0,32), px wc*64 + [0,64), K=64
        f32x4 ka[2][4];
#pragma unroll
        for (int m = 0; m < 2; ++m)
#pragma unroll
            for (int n = 0; n < 4; ++n) ka[m][n] = f32x4{0.f, 0.f, 0.f, 0.f};
#pragma unroll
        for (int kk = 0; kk < 2; ++kk) {
            bf16x8 a[2];
#pragma unroll
            for (int m = 0; m < 2; ++m)
                a[m] = *(const bf16x8*)(G2p +
                        (size_t)(chunk * 64 + wr * 32 + m * 16 + lx) * 64 + kk * 32 + ls * 8);
#pragma unroll
            for (int n = 0; n < 4; ++n)
#pragma unroll
                for (int m = 0; m < 2; ++m)
                    ka[m][n] = __builtin_amdgcn_mfma_f32_16x16x32_bf16(a[m], bv[kk][n], ka[m][n], 0, 0, 0);
        }
        // epilogue: + g2b, write kern TRANSPOSED [pxl][rl] with 16B-granule XOR swizzle
#pragma unroll
        for (int m = 0; m < 2; ++m) {
            const float4 bb4 = *(const float4*)(g2b + chunk * 64 + wr * 32 + m * 16 + ls * 4);
            const float bb[4] = {bb4.x, bb4.y, bb4.z, bb4.w};
            const int rl0 = wr * 32 + m * 16 + ls * 4;   // multiple of 4
            const int gr = rl0 >> 3, sub = rl0 & 7;      // sub in {0,4}
#pragma unroll
            for (int n = 0; n < 4; ++n) {
                const int pxl = wc * 64 + n * 16 + lx;
                u32x2 pk;
                pk[0] = (unsigned)f2bf(ka[m][n][0] + bb[0]) |
                        ((unsigned)f2bf(ka[m][n][1] + bb[1]) << 16);
                pk[1] = (unsigned)f2bf(ka[m][n][2] + bb[2]) |
                        ((unsigned)f2bf(ka[m][n][3] + bb[3]) << 16);
                *(u32x2*)(smU + pxl * 64 + ((gr ^ (pxl & 7)) << 3) + sub) = pk;
            }
        }
        __syncthreads();
        // load own px column: all 64 rows as 8 b128
        u32x4 kvr[8];
#pragma unroll
        for (int k = 0; k < 8; ++k)
            kvr[k] = *(const u32x4*)(smU + px * 64 + ((k ^ (px & 7)) << 3));
        // apply: rows of this chunk whose channel parity == chalf (c,t compile-time)
#pragma unroll
        for (int rl = 0; rl < 64; ++rl) {
            const int r = chunk * 64 + rl;         // compile-time
            const int c = r / 9, t = r - c * 9;    // compile-time
            const int s = c >> 1;
            if ((c & 1) == chalf) {
                float kv = bfhalf(kvr[rl >> 3][(rl & 7) >> 1], rl & 1);
                float pv = bf2f(smFB[c * 180 + (ty + t / 3) * 18 + tx + (t % 3)]);
                acc[s] = fmaf(kv, pv, acc[s]);
            }
        }
        __syncthreads();                       // apply reads done before next epilogue
    }

    // out = fb1 (gated center) + dynconv; transpose through smU -> blocked b128
#pragma unroll
    for (int s = 0; s < 32; ++s) {
        const int c = 2 * s + chalf;
        float res = bf2f(smFB[c * 180 + (ty + 1) * 18 + (tx + 1)]);
        smU[c * 128 + px] = f2bf(acc[s] + res);
    }
    __syncthreads();
#pragma unroll
    for (int it = 0; it < 4; ++it) {
        int i = tid + it * 256;
        int p = i & 127, oct = i >> 7;
        u32x4 pk;
#pragma unroll
        for (int q = 0; q < 4; ++q)
            pk[q] = (unsigned)smU[(oct * 8 + 2 * q) * 128 + p] |
                    ((unsigned)smU[(oct * 8 + 2 * q + 1) * 128 + p] << 16);
        *(u32x4*)(outb + ((size_t)(b * 8 + oct) * HW + (by + (p >> 4)) * Wn + bx + (p & 15)) * 8) = pk;
    }
}

// ---------------- final fusion via MFMA: out = Fw @ concat(ev*(1+sc), fb2) -----
__global__ __launch_bounds__(256, 3) void fuse_mfma_k(
        const unsigned short* __restrict__ evb, const float* __restrict__ scale,
        const unsigned short* __restrict__ fb2b, const unsigned short* __restrict__ Fwp,
        float* __restrict__ out) {
    __shared__ unsigned short smF[16384];   // [oct16][px128][8ci] 32 KB
    const int bid = blockIdx.x;
    const int b = bid >> 7, px0 = (bid & 127) << 7;
    const int tid = threadIdx.x;
    const int lane = tid & 63, w = tid >> 6;
    const int lx = lane & 15, ls = lane >> 4;
    const int wr = w & 1, wc = w >> 1;
    const float* sc = scale + b * HW + px0;

    // fb2 half: async direct-to-LDS (issue first so it overlaps the ev compute)
#pragma unroll
    for (int it = 4; it < 8; ++it) {
        int slot = tid + it * 256;
        int oct = slot >> 7, pxl = slot & 127;
        gl_lds16(fb2b + ((size_t)(b * 8 + oct - 8) * HW + px0 + pxl) * 8, smF + slot * 8);
    }
    // ev half: scaled through registers
#pragma unroll
    for (int it = 0; it < 4; ++it) {
        int slot = tid + it * 256;
        int oct = slot >> 7, pxl = slot & 127;
        u32x4 v = *(const u32x4*)(evb + ((size_t)(b * 8 + oct) * HW + px0 + pxl) * 8);
        float s = 1.f + sc[pxl];
#pragma unroll
        for (int q = 0; q < 4; ++q)
            v[q] = (unsigned)f2bf(bfhalf(v[q], 0) * s) |
                   ((unsigned)f2bf(bfhalf(v[q], 1) * s) << 16);
        ((u32x4*)smF)[slot] = v;
    }
    __syncthreads();

    f32x4 acc[4][4];
#pragma unroll
    for (int m = 0; m < 4; ++m)
#pragma unroll
        for (int n = 0; n < 4; ++n) acc[m][n] = f32x4{0.f, 0.f, 0.f, 0.f};

#pragma unroll
    for (int kk = 0; kk < 4; ++kk) {
        bf16x8 a[4];
#pragma unroll
        for (int m = 0; m < 4; ++m)
            a[m] = *(const bf16x8*)(Fwp + (size_t)(wr * 64 + m * 16 + lx) * 128 + kk * 32 + ls * 8);
#pragma unroll
        for (int n = 0; n < 4; ++n) {
            bf16x8 bv = *(const bf16x8*)(smF + ((kk * 4 + ls) * 128 + wc * 64 + n * 16 + lx) * 8);
#pragma unroll
            for (int m = 0; m < 4; ++m)
                acc[m][n] = __builtin_amdgcn_mfma_f32_16x16x32_bf16(a[m], bv, acc[m][n], 0, 0, 0);
        }
    }

    const size_t ob = (size_t)b * 2 * CHW + px0 + wc * 64;
#pragma unroll
    for (int m = 0; m < 4; ++m)
#pragma unroll
        for (int n = 0; n < 4; ++n)
#pragma unroll
            for (int j = 0; j < 4; ++j) {
                const int co = wr * 64 + m * 16 + ls * 4 + j;
                out[ob + (size_t)co * HW + n * 16 + lx] = acc[m][n][j];
            }
}

// ---------------- host launch ----------------
extern "C" void kernel_launch(void* const* d_in, const int* in_sizes, int n_in,
                              void* d_out, int out_size, void* d_ws, size_t ws_size,
                              hipStream_t stream) {
    const float* f_event = (const float*)d_in[0];
    const float* f_blur  = (const float*)d_in[1];
    const float* Wt1 = (const float*)d_in[2];
    const float* Wt2 = (const float*)d_in[3];
    const float* Wt3 = (const float*)d_in[4];
    const float* A1  = (const float*)d_in[5];
    const float* b1  = (const float*)d_in[6];
    const float* A2  = (const float*)d_in[7];
    const float* b2  = (const float*)d_in[8];
    const float* G1  = (const float*)d_in[9];
    const float* g1b = (const float*)d_in[10];
    const float* G2  = (const float*)d_in[11];
    const float* g2b = (const float*)d_in[12];
    const float* Rw  = (const float*)d_in[13];
    const float* rb  = (const float*)d_in[14];
    const float* S1  = (const float*)d_in[15];
    const float* S2  = (const float*)d_in[16];
    const float* Ew  = (const float*)d_in[17];
    const float* eb  = (const float*)d_in[18];
    const float* Fw  = (const float*)d_in[19];
    float* out = (float*)d_out;

    float* ws    = (float*)d_ws;
    float* w0    = ws;                         // 512
    float* w0s   = w0 + 512;                   // 512
    float* rgb   = w0s + 512;                  // 131072
    float* comp  = rgb + Bn * HW;              // 262144
    float* scale = comp + 2 * Bn * HW;         // 131072
    unsigned short* wprep = (unsigned short*)(scale + Bn * HW);  // 6 x 36864
    unsigned short* G2p = wprep + 6 * 36864;                     // 36864
    unsigned short* Fwp = G2p + 36864;                           // 16384
    unsigned short* zpad = Fwp + 16384;        // 64 shorts (zero page)
    unsigned short* B0 = zpad + 64;            // evblk
    unsigned short* B1 = B0 + NB;              // f0blk
    unsigned short* B2 = B1 + NB;              // t1blk
    unsigned short* B3 = B2 + NB;              // fusedblk -> fb2blk
    unsigned short* B4 = B3 + NB;              // hblk
    unsigned short* B5 = B4 + NB;              // fbblk (blocked f_blur)
    unsigned short* B6 = B5 + NB;              // s1blk

    // 0. weight preps + input blocking
    prep_w_k<<<dim3(144, 6), 256, 0, stream>>>(Wt1, Wt2, Wt3, G1, S1, S2, wprep);
    prep2_k<<<208, 256, 0, stream>>>(G2, Fw, G2p, Fwp, zpad);
    pre_blk_k<<<4096, 256, 0, stream>>>(f_event, f_blur, B0, B1, B5);
    // 1. L1: t1 = relu(conv(f0,Wt1)); h = relu(conv(ev,G1)+g1b); s1 = relu(conv(ev,S1))
    conv3x3_l1_blk<<<dim3(8, 8, 24), 256, 0, stream>>>(
        B1, B0, wprep + 0 * 36864, wprep + 3 * 36864, wprep + 4 * 36864, g1b,
        B2, B4, B6, zpad);
    // 2. L2: fused = conv(t1, Wt2); comp = chan-max/mean(conv(s1, S2))
    conv3x3_l2_blk<<<dim3(8, 8, 16), 256, 0, stream>>>(
        B2, B6, wprep + 1 * 36864, wprep + 5 * 36864, B3, comp, zpad);
    // 3. SE gate
    mean_hw_blk<<<Bn * 8, 256, 0, stream>>>(B3, w0);
    mlp_k<<<Bn, 128, 0, stream>>>(w0, A1, b1, A2, b2, w0s);
    // 4. merged: rgb gate conv (z<8) + scale_e = sigmoid(conv5x5(comp)) (z>=8)
    rgb_sconv_k<<<dim3(8, 8, 16), 256, 0, stream>>>(
        B3, wprep + 2 * 36864, Rw, rb, rgb, comp, Ew, eb, scale, zpad);
    // 5. fb2 = fb1 + dynconv(fb1, kern(h)), fb1 gating fused into staging
    dynfused_k<<<dim3(8, 16, Bn), 256, 0, stream>>>(B5, B4, G2p, g2b, w0s, rgb, B3);
    // 6. out = Fw @ concat(ev*(1+scale_e), fb2)
    fuse_mfma_k<<<Bn * HW / 128, 256, 0, stream>>>(B0, scale, B3, Fwp, out);
}

// Round 17
// 218.800 us; speedup vs baseline: 1.0617x; 1.0046x over previous
//
#include <hip/hip_runtime.h>
#include <math.h>

constexpr int Bn = 8, Cn = 64, Hn = 128, Wn = 128;
constexpr int HW  = Hn * Wn;      // 16384
constexpr int CHW = Cn * HW;      // 1048576
constexpr size_t NB = (size_t)Bn * CHW;   // elems per blocked tensor

typedef float  f32x4  __attribute__((ext_vector_type(4)));
typedef __bf16 bf16x8 __attribute__((ext_vector_type(8)));
typedef unsigned int u32x4 __attribute__((ext_vector_type(4)));
typedef unsigned int u32x2 __attribute__((ext_vector_type(2)));

static __device__ __forceinline__ unsigned short f2bf(float f) {
    unsigned u = __builtin_bit_cast(unsigned, f);
    u = (u + 0x7FFF + ((u >> 16) & 1)) >> 16;
    return (unsigned short)u;
}
static __device__ __forceinline__ float bf2f(unsigned short v) {
    unsigned u = (unsigned)v << 16;
    return __builtin_bit_cast(float, u);
}
static __device__ __forceinline__ float bfhalf(unsigned u, int hi) {
    unsigned r = hi ? (u & 0xffff0000u) : (u << 16);
    return __builtin_bit_cast(float, r);
}

// async global->LDS 16B (direct-to-shared); falls back to reg copy if unavailable
static __device__ __forceinline__ void gl_lds16(const unsigned short* g, unsigned short* l) {
#if defined(__has_builtin) && __has_builtin(__builtin_amdgcn_global_load_lds)
    __builtin_amdgcn_global_load_lds(
        (const __attribute__((address_space(1))) void*)g,
        (__attribute__((address_space(3))) void*)l, 16, 0, 0);
#else
    *(u32x4*)l = *(const u32x4*)g;
#endif
}

// ---------------- weight prep: OIHW fp32 -> [kk][s][t][co][8cj] bf16 ----------------
__global__ void prep_w_k(const float* __restrict__ W0, const float* __restrict__ W1,
                         const float* __restrict__ W2, const float* __restrict__ W3,
                         const float* __restrict__ W4, const float* __restrict__ W5,
                         unsigned short* __restrict__ dst) {
    int i = blockIdx.x * 256 + threadIdx.x;
    if (i >= 36864) return;
    const float* W = W0;
    switch (blockIdx.y) {
        case 1: W = W1; break; case 2: W = W2; break;
        case 3: W = W3; break; case 4: W = W4; break; case 5: W = W5; break;
        default: break;
    }
    int cj = i & 7;
    int rest = i >> 3;
    int co = rest & 63;
    rest >>= 6;              // (kk*4+s)*9 + t
    int t  = rest % 9;
    int hs = rest / 9;       // 0..7
    int ci = hs * 8 + cj;
    dst[(size_t)blockIdx.y * 36864 + i] = f2bf(W[(co * 64 + ci) * 9 + t]);
}

// ---------------- prep2: G2/Fw -> bf16; zero-page init ----------------
__global__ void prep2_k(const float* __restrict__ G2, const float* __restrict__ Fw,
                        unsigned short* __restrict__ G2p, unsigned short* __restrict__ Fwp,
                        unsigned short* __restrict__ zp) {
    int i = blockIdx.x * 256 + threadIdx.x;
    if (i < 64) zp[i] = 0;
    if (i < 36864) G2p[i] = f2bf(G2[i]);
    else if (i < 36864 + 16384) Fwp[i - 36864] = f2bf(Fw[i - 36864]);
}

// ---------------- pre: blocked bf16 of f_event, f_event+f_blur, f_blur ----------
__global__ void pre_blk_k(const float* __restrict__ fe, const float* __restrict__ fb,
                          unsigned short* __restrict__ evb, unsigned short* __restrict__ f0b,
                          unsigned short* __restrict__ fbb) {
    int i = blockIdx.x * 256 + threadIdx.x;       // (b, oct, px)
    int px = i & 16383;
    int oct = (i >> 14) & 7;
    int b = i >> 17;
    const float* pe = fe + (size_t)b * CHW + (size_t)oct * 8 * HW + px;
    const float* pb = fb + (size_t)b * CHW + (size_t)oct * 8 * HW + px;
    u32x4 ev, f0, fbv;
#pragma unroll
    for (int q = 0; q < 4; ++q) {
        float e0 = pe[(size_t)(2 * q) * HW],     b0 = pb[(size_t)(2 * q) * HW];
        float e1 = pe[(size_t)(2 * q + 1) * HW], b1 = pb[(size_t)(2 * q + 1) * HW];
        ev[q]  = (unsigned)f2bf(e0) | ((unsigned)f2bf(e1) << 16);
        f0[q]  = (unsigned)f2bf(e0 + b0) | ((unsigned)f2bf(e1 + b1) << 16);
        fbv[q] = (unsigned)f2bf(b0) | ((unsigned)f2bf(b1) << 16);
    }
    const size_t o = ((size_t)(b * 8 + oct) * HW + px) * 8;
    *(u32x4*)(evb + o) = ev;
    *(u32x4*)(f0b + o) = f0;
    *(u32x4*)(fbb + o) = fbv;
}

// ---------------- L1: three independent RELU convs in one launch -------------------
__global__ __launch_bounds__(256, 3) void conv3x3_l1_blk(
        const unsigned short* __restrict__ f0, const unsigned short* __restrict__ ev,
        const unsigned short* __restrict__ Wt1g, const unsigned short* __restrict__ G1g,
        const unsigned short* __restrict__ S1g, const float* __restrict__ g1b,
        unsigned short* __restrict__ out_t1, unsigned short* __restrict__ out_h,
        unsigned short* __restrict__ out_s1, const unsigned short* __restrict__ zp) {
    __shared__ unsigned short smIn[20736];
    const int z = blockIdx.z;
    const int b = z & 7, sel = z >> 3;
    const unsigned short* in = (sel == 0) ? f0 : ev;
    const unsigned short* Wg = (sel == 0) ? Wt1g : ((sel == 1) ? G1g : S1g);
    unsigned short* out = (sel == 0) ? out_t1 : ((sel == 1) ? out_h : out_s1);
    const int by = blockIdx.y << 4, bx = blockIdx.x << 4;
    const int tid = threadIdx.x;
    const int lane = tid & 63, w = tid >> 6;
    const int lx = lane & 15, ls = lane >> 4;

    for (int idx = tid; idx < 2592; idx += 256) {
        int oct = idx / 324;
        int p   = idx - oct * 324;
        int yy = p / 18, xx = p - yy * 18;
        int gy = by + yy - 1, gx = bx + xx - 1;
        const unsigned short* src =
            ((unsigned)gy < (unsigned)Hn && (unsigned)gx < (unsigned)Wn)
            ? in + ((size_t)(b * 8 + oct) * HW + gy * Wn + gx) * 8 : zp;
        gl_lds16(src, smIn + idx * 8);
    }
    __syncthreads();

    f32x4 acc[4][4];
#pragma unroll
    for (int m = 0; m < 4; ++m)
#pragma unroll
        for (int n = 0; n < 4; ++n) acc[m][n] = f32x4{0.f, 0.f, 0.f, 0.f};

#pragma unroll
    for (int ky = 0; ky < 3; ++ky)
#pragma unroll
    for (int kx = 0; kx < 3; ++kx) {
        const int t = ky * 3 + kx;
#pragma unroll
        for (int kk = 0; kk < 2; ++kk) {
            bf16x8 a[4];
            const unsigned short* wbase = Wg + kk * 18432 + ls * 4608 + t * 512 + lx * 8;
#pragma unroll
            for (int m = 0; m < 4; ++m)
                a[m] = *(const bf16x8*)(wbase + m * 128);
            const unsigned short* ibase =
                smIn + ((kk * 4 + ls) * 324 + (4 * w + ky) * 18 + lx + kx) * 8;
#pragma unroll
            for (int n = 0; n < 4; ++n) {
                bf16x8 bf = *(const bf16x8*)(ibase + n * 144);
#pragma unroll
                for (int m = 0; m < 4; ++m)
                    acc[m][n] = __builtin_amdgcn_mfma_f32_16x16x32_bf16(
                        a[m], bf, acc[m][n], 0, 0, 0);
            }
        }
    }

    const int y0 = by + 4 * w;
#pragma unroll
    for (int m = 0; m < 4; ++m) {
        float bv[4] = {0.f, 0.f, 0.f, 0.f};
        if (sel == 1) {
            float4 b4 = *(const float4*)(g1b + 16 * m + ls * 4);
            bv[0] = b4.x; bv[1] = b4.y; bv[2] = b4.z; bv[3] = b4.w;
        }
        const size_t rowb = (size_t)(b * 8 + m * 2 + (ls >> 1)) * HW;
        const int j0 = (ls & 1) * 4;
#pragma unroll
        for (int n = 0; n < 4; ++n) {
            const size_t pofs = rowb + (size_t)(y0 + n) * Wn + bx + lx;
            float vr[4];
#pragma unroll
            for (int r = 0; r < 4; ++r)
                vr[r] = fmaxf(acc[m][n][r] + bv[r], 0.f);
            u32x2 pk;
            pk[0] = (unsigned)f2bf(vr[0]) | ((unsigned)f2bf(vr[1]) << 16);
            pk[1] = (unsigned)f2bf(vr[2]) | ((unsigned)f2bf(vr[3]) << 16);
            *(u32x2*)(out + pofs * 8 + j0) = pk;
        }
    }
}

// ---------------- L2: Wt2 conv (store) + S2 conv (COMP epilogue) -------------------
__global__ __launch_bounds__(256, 3) void conv3x3_l2_blk(
        const unsigned short* __restrict__ t1, const unsigned short* __restrict__ s1,
        const unsigned short* __restrict__ Wt2g, const unsigned short* __restrict__ S2g,
        unsigned short* __restrict__ out_f, float* __restrict__ comp,
        const unsigned short* __restrict__ zp) {
    __shared__ unsigned short smIn[20736];
    const int z = blockIdx.z;
    const int b = z & 7, sel = z >> 3;
    const unsigned short* in = (sel == 0) ? t1 : s1;
    const unsigned short* Wg = (sel == 0) ? Wt2g : S2g;
    const int by = blockIdx.y << 4, bx = blockIdx.x << 4;
    const int tid = threadIdx.x;
    const int lane = tid & 63, w = tid >> 6;
    const int lx = lane & 15, ls = lane >> 4;

    for (int idx = tid; idx < 2592; idx += 256) {
        int oct = idx / 324;
        int p   = idx - oct * 324;
        int yy = p / 18, xx = p - yy * 18;
        int gy = by + yy - 1, gx = bx + xx - 1;
        const unsigned short* src =
            ((unsigned)gy < (unsigned)Hn && (unsigned)gx < (unsigned)Wn)
            ? in + ((size_t)(b * 8 + oct) * HW + gy * Wn + gx) * 8 : zp;
        gl_lds16(src, smIn + idx * 8);
    }
    __syncthreads();

    f32x4 acc[4][4];
#pragma unroll
    for (int m = 0; m < 4; ++m)
#pragma unroll
        for (int n = 0; n < 4; ++n) acc[m][n] = f32x4{0.f, 0.f, 0.f, 0.f};

#pragma unroll
    for (int ky = 0; ky < 3; ++ky)
#pragma unroll
    for (int kx = 0; kx < 3; ++kx) {
        const int t = ky * 3 + kx;
#pragma unroll
        for (int kk = 0; kk < 2; ++kk) {
            bf16x8 a[4];
            const unsigned short* wbase = Wg + kk * 18432 + ls * 4608 + t * 512 + lx * 8;
#pragma unroll
            for (int m = 0; m < 4; ++m)
                a[m] = *(const bf16x8*)(wbase + m * 128);
            const unsigned short* ibase =
                smIn + ((kk * 4 + ls) * 324 + (4 * w + ky) * 18 + lx + kx) * 8;
#pragma unroll
            for (int n = 0; n < 4; ++n) {
                bf16x8 bf = *(const bf16x8*)(ibase + n * 144);
#pragma unroll
                for (int m = 0; m < 4; ++m)
                    acc[m][n] = __builtin_amdgcn_mfma_f32_16x16x32_bf16(
                        a[m], bf, acc[m][n], 0, 0, 0);
            }
        }
    }

    const int y0 = by + 4 * w;
    if (sel == 0) {
#pragma unroll
        for (int m = 0; m < 4; ++m) {
            const size_t rowb = (size_t)(b * 8 + m * 2 + (ls >> 1)) * HW;
            const int j0 = (ls & 1) * 4;
#pragma unroll
            for (int n = 0; n < 4; ++n) {
                const size_t pofs = rowb + (size_t)(y0 + n) * Wn + bx + lx;
                u32x2 pk;
                pk[0] = (unsigned)f2bf(acc[m][n][0]) | ((unsigned)f2bf(acc[m][n][1]) << 16);
                pk[1] = (unsigned)f2bf(acc[m][n][2]) | ((unsigned)f2bf(acc[m][n][3]) << 16);
                *(u32x2*)(out_f + pofs * 8 + j0) = pk;
            }
        }
    } else {
        float gs[4], gm[4];
#pragma unroll
        for (int n = 0; n < 4; ++n) { gs[n] = 0.f; gm[n] = -1e30f; }
#pragma unroll
        for (int m = 0; m < 4; ++m)
#pragma unroll
            for (int r = 0; r < 4; ++r)
#pragma unroll
                for (int n = 0; n < 4; ++n) {
                    float v = acc[m][n][r];
                    gm[n] = fmaxf(gm[n], v);
                    gs[n] += v;
                }
#pragma unroll
        for (int n = 0; n < 4; ++n) {
            float s = gs[n], mx = gm[n];
            s += __shfl_xor(s, 16);
            s += __shfl_xor(s, 32);
            mx = fmaxf(mx, __shfl_xor(mx, 16));
            mx = fmaxf(mx, __shfl_xor(mx, 32));
            if (ls == 0) {
                const size_t o = (size_t)b * 2 * HW + (size_t)(y0 + n) * Wn + bx + lx;
                comp[o]      = mx;
                comp[o + HW] = s * (1.f / 64.f);
            }
        }
    }
}

// ---------------- merged: rgb-gate conv (z<8) + sconv5 (z>=8) ----------------------
__global__ __launch_bounds__(256, 3) void rgb_sconv_k(
        const unsigned short* __restrict__ in, const unsigned short* __restrict__ Wg,
        const float* __restrict__ gw, const float* __restrict__ gb,
        float* __restrict__ gout,
        const float* __restrict__ comp, const float* __restrict__ Ew,
        const float* __restrict__ eb, float* __restrict__ scale,
        const unsigned short* __restrict__ zp) {
    __shared__ unsigned short smIn[20736];
    const int z = blockIdx.z;
    if (z >= 8) {
        // sconv5: linear block (z-8)*64 + by*8 + bx
        int id = (((z - 8) * 64) + blockIdx.y * 8 + blockIdx.x) * 256 + threadIdx.x;
        int sb = id >> 14, p = id & 16383;
        int y = p >> 7, x = p & 127;
        const float* cb = comp + (size_t)sb * 2 * HW;
        float sacc = eb[0];
#pragma unroll
        for (int ch = 0; ch < 2; ++ch)
#pragma unroll
            for (int ky = 0; ky < 5; ++ky) {
                int gy = y + ky - 2;
                if ((unsigned)gy >= (unsigned)Hn) continue;
#pragma unroll
                for (int kx = 0; kx < 5; ++kx) {
                    int gx = x + kx - 2;
                    if ((unsigned)gx >= (unsigned)Wn) continue;
                    sacc = fmaf(Ew[ch * 25 + ky * 5 + kx], cb[ch * HW + gy * Wn + gx], sacc);
                }
            }
        scale[id] = 1.f / (1.f + expf(-sacc));
        return;
    }
    const int b = z;
    const int by = blockIdx.y << 4, bx = blockIdx.x << 4;
    const int tid = threadIdx.x;
    const int lane = tid & 63, w = tid >> 6;
    const int lx = lane & 15, ls = lane >> 4;

    for (int idx = tid; idx < 2592; idx += 256) {
        int oct = idx / 324;
        int p   = idx - oct * 324;
        int yy = p / 18, xx = p - yy * 18;
        int gy = by + yy - 1, gx = bx + xx - 1;
        const unsigned short* src =
            ((unsigned)gy < (unsigned)Hn && (unsigned)gx < (unsigned)Wn)
            ? in + ((size_t)(b * 8 + oct) * HW + gy * Wn + gx) * 8 : zp;
        gl_lds16(src, smIn + idx * 8);
    }
    __syncthreads();

    f32x4 acc[4][4];
#pragma unroll
    for (int m = 0; m < 4; ++m)
#pragma unroll
        for (int n = 0; n < 4; ++n) acc[m][n] = f32x4{0.f, 0.f, 0.f, 0.f};

#pragma unroll
    for (int ky = 0; ky < 3; ++ky)
#pragma unroll
    for (int kx = 0; kx < 3; ++kx) {
        const int t = ky * 3 + kx;
#pragma unroll
        for (int kk = 0; kk < 2; ++kk) {
            bf16x8 a[4];
            const unsigned short* wbase = Wg + kk * 18432 + ls * 4608 + t * 512 + lx * 8;
#pragma unroll
            for (int m = 0; m < 4; ++m)
                a[m] = *(const bf16x8*)(wbase + m * 128);
            const unsigned short* ibase =
                smIn + ((kk * 4 + ls) * 324 + (4 * w + ky) * 18 + lx + kx) * 8;
#pragma unroll
            for (int n = 0; n < 4; ++n) {
                bf16x8 bf = *(const bf16x8*)(ibase + n * 144);
#pragma unroll
                for (int m = 0; m < 4; ++m)
                    acc[m][n] = __builtin_amdgcn_mfma_f32_16x16x32_bf16(
                        a[m], bf, acc[m][n], 0, 0, 0);
            }
        }
    }

    // epilogue: fused2 = in + relu(conv); rgb = sum_c gw[c]*fused2 + gb
    const int y0 = by + 4 * w;
    float gs[4];
#pragma unroll
    for (int n = 0; n < 4; ++n) gs[n] = 0.f;
#pragma unroll
    for (int m = 0; m < 4; ++m) {
        float4 rw4 = *(const float4*)(gw + 16 * m + ls * 4);
        const float rwf[4] = {rw4.x, rw4.y, rw4.z, rw4.w};
        const size_t rowb = (size_t)(b * 8 + m * 2 + (ls >> 1)) * HW;
        const int j0 = (ls & 1) * 4;
#pragma unroll
        for (int n = 0; n < 4; ++n) {
            const size_t pofs = rowb + (size_t)(y0 + n) * Wn + bx + lx;
            u32x2 rin = *(const u32x2*)(in + pofs * 8 + j0);
#pragma unroll
            for (int r = 0; r < 4; ++r) {
                float v = fmaxf(acc[m][n][r], 0.f) + bfhalf(rin[r >> 1], r & 1);
                gs[n] = fmaf(rwf[r], v, gs[n]);
            }
        }
    }
#pragma unroll
    for (int n = 0; n < 4; ++n) {
        float s = gs[n];
        s += __shfl_xor(s, 16);
        s += __shfl_xor(s, 32);
        if (ls == 0)
            gout[(size_t)b * HW + (size_t)(y0 + n) * Wn + bx + lx] = s + gb[0];
    }
}

// ---------------- mean over H,W per (b,oct) from blocked bf16 ----------------
__global__ void mean_hw_blk(const unsigned short* __restrict__ in, float* __restrict__ w0) {
    __shared__ float red[256][8];
    const int bo = blockIdx.x;                 // b*8+oct
    const int tid = threadIdx.x;
    const unsigned short* p = in + (size_t)bo * HW * 8;
    float s[8];
#pragma unroll
    for (int j = 0; j < 8; ++j) s[j] = 0.f;
    for (int it = 0; it < 64; ++it) {
        u32x4 v = *(const u32x4*)(p + (size_t)(tid + it * 256) * 8);
#pragma unroll
        for (int j = 0; j < 8; ++j) s[j] += bfhalf(v[j >> 1], j & 1);
    }
#pragma unroll
    for (int j = 0; j < 8; ++j) red[tid][j] = s[j];
    __syncthreads();
    for (int off = 128; off > 0; off >>= 1) {
        if (tid < off)
#pragma unroll
            for (int j = 0; j < 8; ++j) red[tid][j] += red[tid + off][j];
        __syncthreads();
    }
    if (tid < 8) w0[bo * 8 + tid] = red[0][tid] * (1.f / 16384.f);
}

// ---------------- SE MLP ----------------
__global__ void mlp_k(const float* __restrict__ w0, const float* __restrict__ A1,
                      const float* __restrict__ b1, const float* __restrict__ A2,
                      const float* __restrict__ b2, float* __restrict__ w0s) {
    int b = blockIdx.x, t = threadIdx.x;       // 128 threads
    __shared__ float w0r[64], hid[128];
    if (t < 64) w0r[t] = w0[b * 64 + t];
    __syncthreads();
    float s = b1[t];
    for (int c = 0; c < 64; ++c) s = fmaf(A1[t * 64 + c], w0r[c], s);
    hid[t] = fmaxf(s, 0.f);
    __syncthreads();
    if (t < 64) {
        float s2 = b2[t];
        for (int j = 0; j < 128; ++j) s2 = fmaf(A2[t * 128 + j], hid[j], s2);
        w0s[b * 64 + t] = 1.f / (1.f + expf(-s2));
    }
}

// ---------------- fused dynamic conv (apply moved past barrier for overlap) --------
__global__ __launch_bounds__(256, 4) void dynfused_k(
        const unsigned short* __restrict__ fbb, const unsigned short* __restrict__ hb,
        const unsigned short* __restrict__ G2p, const float* __restrict__ g2b,
        const float* __restrict__ w0s, const float* __restrict__ rgb,
        unsigned short* __restrict__ outb) {
    __shared__ unsigned short smU[8192];       // union: h staging -> kern[px][64 swz] -> out
    __shared__ unsigned short smFB[11520];     // [c64][180] gated patch, 22.5 KB
    const int b  = blockIdx.z;
    const int by = blockIdx.y << 3, bx = blockIdx.x << 4;
    const int tid = threadIdx.x;
    const int lane = tid & 63, w = tid >> 6;
    const int lx = lane & 15, ls = lane >> 4;
    const int wr = w & 1, wc = w >> 1;
    const int px = tid & 127;
    const int chalf = __builtin_amdgcn_readfirstlane(tid >> 7);  // wave-uniform
    const int ty = px >> 4, tx = px & 15;

    // stage h: async direct-to-LDS -> smU [oct][px][8]
#pragma unroll
    for (int it = 0; it < 4; ++it) {
        int i = tid + it * 256;
        int p = i & 127, oct = i >> 7;
        gl_lds16(hb + ((size_t)(b * 8 + oct) * HW + (by + (p >> 4)) * Wn + bx + (p & 15)) * 8,
                 smU + i * 8);
    }
    // stage fb patch with fb1 gating: blocked b128 load, gate, scatter to [c][180]
    const float* rgbb = rgb + (size_t)b * HW;
    for (int i = tid; i < 1440; i += 256) {
        int oct = i / 180, p = i - oct * 180;
        int pr = p / 18, pc = p - pr * 18;
        int gy = min(max(by + pr - 1, 0), Hn - 1);
        int gx = min(max(bx + pc - 1, 0), Wn - 1);
        u32x4 v = *(const u32x4*)(fbb + ((size_t)(b * 8 + oct) * HW + gy * Wn + gx) * 8);
        float g = 1.f + rgbb[gy * Wn + gx];
        float4 s0 = *(const float4*)(w0s + b * 64 + oct * 8);
        float4 s1 = *(const float4*)(w0s + b * 64 + oct * 8 + 4);
        const float sc[8] = {1.f + s0.x, 1.f + s0.y, 1.f + s0.z, 1.f + s0.w,
                             1.f + s1.x, 1.f + s1.y, 1.f + s1.z, 1.f + s1.w};
#pragma unroll
        for (int j = 0; j < 8; ++j)
            smFB[(oct * 8 + j) * 180 + p] = f2bf(bfhalf(v[j >> 1], j & 1) * sc[j] * g);
    }
    __syncthreads();

    // hoist b-frags (chunk-invariant) from smU to registers
    bf16x8 bv[2][4];
#pragma unroll
    for (int kk = 0; kk < 2; ++kk)
#pragma unroll
        for (int n = 0; n < 4; ++n)
            bv[kk][n] = *(const bf16x8*)(smU + ((kk * 4 + ls) * 128 + wc * 64 + n * 16 + lx) * 8);
    __syncthreads();                           // all reads done before smU becomes kern

    float acc[32];
#pragma unroll
    for (int s = 0; s < 32; ++s) acc[s] = 0.f;

#pragma unroll
    for (int chunk = 0; chunk < 9; ++chunk) {
        // GEMM: rows chunk*64 + wr*32 + [0,32), px wc*64 + [0,64), K=64
        f32x4 ka[2][4];
#pragma unroll
        for (int m = 0; m < 2; ++m)
#pragma unroll
            for (int n = 0; n < 4; ++n) ka[m][n] = f32x4{0.f, 0.f, 0.f, 0.f};
#pragma unroll
        for (int kk = 0; kk < 2; ++kk) {
            bf16x8 a[2];
#pragma unroll
            for (int m = 0; m < 2; ++m)
                a[m] = *(const bf16x8*)(G2p +
                        (size_t)(chunk * 64 + wr * 32 + m * 16 + lx) * 64 + kk * 32 + ls * 8);
#pragma unroll
            for (int n = 0; n < 4; ++n)
#pragma unroll
                for (int m = 0; m < 2; ++m)
                    ka[m][n] = __builtin_amdgcn_mfma_f32_16x16x32_bf16(a[m], bv[kk][n], ka[m][n], 0, 0, 0);
        }
        // epilogue: + g2b, write kern TRANSPOSED [pxl][rl] with 16B-granule XOR swizzle
#pragma unroll
        for (int m = 0; m < 2; ++m) {
            const float4 bb4 = *(const float4*)(g2b + chunk * 64 + wr * 32 + m * 16 + ls * 4);
            const float bb[4] = {bb4.x, bb4.y, bb4.z, bb4.w};
            const int rl0 = wr * 32 + m * 16 + ls * 4;   // multiple of 4
            const int gr = rl0 >> 3, sub = rl0 & 7;      // sub in {0,4}
#pragma unroll
            for (int n = 0; n < 4; ++n) {
                const int pxl = wc * 64 + n * 16 + lx;
                u32x2 pk;
                pk[0] = (unsigned)f2bf(ka[m][n][0] + bb[0]) |
                        ((unsigned)f2bf(ka[m][n][1] + bb[1]) << 16);
                pk[1] = (unsigned)f2bf(ka[m][n][2] + bb[2]) |
                        ((unsigned)f2bf(ka[m][n][3] + bb[3]) << 16);
                *(u32x2*)(smU + pxl * 64 + ((gr ^ (pxl & 7)) << 3) + sub) = pk;
            }
        }
        __syncthreads();
        // load own px column: all 64 rows as 8 b128
        u32x4 kvr[8];
#pragma unroll
        for (int k = 0; k < 8; ++k)
            kvr[k] = *(const u32x4*)(smU + px * 64 + ((k ^ (px & 7)) << 3));
        __syncthreads();                       // kvr loads done -> smU free for next epilogue;
                                               // apply below overlaps next chunk's GEMM
        // apply: rows of this chunk whose channel parity == chalf (c,t compile-time)
#pragma unroll
        for (int rl = 0; rl < 64; ++rl) {
            const int r = chunk * 64 + rl;         // compile-time
            const int c = r / 9, t = r - c * 9;    // compile-time
            const int s = c >> 1;
            if ((c & 1) == chalf) {
                float kv = bfhalf(kvr[rl >> 3][(rl & 7) >> 1], rl & 1);
                float pv = bf2f(smFB[c * 180 + (ty + t / 3) * 18 + tx + (t % 3)]);
                acc[s] = fmaf(kv, pv, acc[s]);
            }
        }
    }

    // out = fb1 (gated center) + dynconv; transpose through smU -> blocked b128
    __syncthreads();                           // last apply done before smU overwrite
#pragma unroll
    for (int s = 0; s < 32; ++s) {
        const int c = 2 * s + chalf;
        float res = bf2f(smFB[c * 180 + (ty + 1) * 18 + (tx + 1)]);
        smU[c * 128 + px] = f2bf(acc[s] + res);
    }
    __syncthreads();
#pragma unroll
    for (int it = 0; it < 4; ++it) {
        int i = tid + it * 256;
        int p = i & 127, oct = i >> 7;
        u32x4 pk;
#pragma unroll
        for (int q = 0; q < 4; ++q)
            pk[q] = (unsigned)smU[(oct * 8 + 2 * q) * 128 + p] |
                    ((unsigned)smU[(oct * 8 + 2 * q + 1) * 128 + p] << 16);
        *(u32x4*)(outb + ((size_t)(b * 8 + oct) * HW + (by + (p >> 4)) * Wn + bx + (p & 15)) * 8) = pk;
    }
}

// ---------------- final fusion via MFMA: out = Fw @ concat(ev*(1+sc), fb2) -----
__global__ __launch_bounds__(256, 3) void fuse_mfma_k(
        const unsigned short* __restrict__ evb, const float* __restrict__ scale,
        const unsigned short* __restrict__ fb2b, const unsigned short* __restrict__ Fwp,
        float* __restrict__ out) {
    __shared__ unsigned short smF[16384];   // [oct16][px128][8ci] 32 KB
    const int bid = blockIdx.x;
    const int b = bid >> 7, px0 = (bid & 127) << 7;
    const int tid = threadIdx.x;
    const int lane = tid & 63, w = tid >> 6;
    const int lx = lane & 15, ls = lane >> 4;
    const int wr = w & 1, wc = w >> 1;
    const float* sc = scale + b * HW + px0;

    // fb2 half: async direct-to-LDS (issue first so it overlaps the ev compute)
#pragma unroll
    for (int it = 4; it < 8; ++it) {
        int slot = tid + it * 256;
        int oct = slot >> 7, pxl = slot & 127;
        gl_lds16(fb2b + ((size_t)(b * 8 + oct - 8) * HW + px0 + pxl) * 8, smF + slot * 8);
    }
    // ev half: scaled through registers
#pragma unroll
    for (int it = 0; it < 4; ++it) {
        int slot = tid + it * 256;
        int oct = slot >> 7, pxl = slot & 127;
        u32x4 v = *(const u32x4*)(evb + ((size_t)(b * 8 + oct) * HW + px0 + pxl) * 8);
        float s = 1.f + sc[pxl];
#pragma unroll
        for (int q = 0; q < 4; ++q)
            v[q] = (unsigned)f2bf(bfhalf(v[q], 0) * s) |
                   ((unsigned)f2bf(bfhalf(v[q], 1) * s) << 16);
        ((u32x4*)smF)[slot] = v;
    }
    __syncthreads();

    f32x4 acc[4][4];
#pragma unroll
    for (int m = 0; m < 4; ++m)
#pragma unroll
        for (int n = 0; n < 4; ++n) acc[m][n] = f32x4{0.f, 0.f, 0.f, 0.f};

#pragma unroll
    for (int kk = 0; kk < 4; ++kk) {
        bf16x8 a[4];
#pragma unroll
        for (int m = 0; m < 4; ++m)
            a[m] = *(const bf16x8*)(Fwp + (size_t)(wr * 64 + m * 16 + lx) * 128 + kk * 32 + ls * 8);
#pragma unroll
        for (int n = 0; n < 4; ++n) {
            bf16x8 bv = *(const bf16x8*)(smF + ((kk * 4 + ls) * 128 + wc * 64 + n * 16 + lx) * 8);
#pragma unroll
            for (int m = 0; m < 4; ++m)
                acc[m][n] = __builtin_amdgcn_mfma_f32_16x16x32_bf16(a[m], bv, acc[m][n], 0, 0, 0);
        }
    }

    const size_t ob = (size_t)b * 2 * CHW + px0 + wc * 64;
#pragma unroll
    for (int m = 0; m < 4; ++m)
#pragma unroll
        for (int n = 0; n < 4; ++n)
#pragma unroll
            for (int j = 0; j < 4; ++j) {
                const int co = wr * 64 + m * 16 + ls * 4 + j;
                out[ob + (size_t)co * HW + n * 16 + lx] = acc[m][n][j];
            }
}

// ---------------- host launch ----------------
extern "C" void kernel_launch(void* const* d_in, const int* in_sizes, int n_in,
                              void* d_out, int out_size, void* d_ws, size_t ws_size,
                              hipStream_t stream) {
    const float* f_event = (const float*)d_in[0];
    const float* f_blur  = (const float*)d_in[1];
    const float* Wt1 = (const float*)d_in[2];
    const float* Wt2 = (const float*)d_in[3];
    const float* Wt3 = (const float*)d_in[4];
    const float* A1  = (const float*)d_in[5];
    const float* b1  = (const float*)d_in[6];
    const float* A2  = (const float*)d_in[7];
    const float* b2  = (const float*)d_in[8];
    const float* G1  = (const float*)d_in[9];
    const float* g1b = (const float*)d_in[10];
    const float* G2  = (const float*)d_in[11];
    const float* g2b = (const float*)d_in[12];
    const float* Rw  = (const float*)d_in[13];
    const float* rb  = (const float*)d_in[14];
    const float* S1  = (const float*)d_in[15];
    const float* S2  = (const float*)d_in[16];
    const float* Ew  = (const float*)d_in[17];
    const float* eb  = (const float*)d_in[18];
    const float* Fw  = (const float*)d_in[19];
    float* out = (float*)d_out;

    float* ws    = (float*)d_ws;
    float* w0    = ws;                         // 512
    float* w0s   = w0 + 512;                   // 512
    float* rgb   = w0s + 512;                  // 131072
    float* comp  = rgb + Bn * HW;              // 262144
    float* scale = comp + 2 * Bn * HW;         // 131072
    unsigned short* wprep = (unsigned short*)(scale + Bn * HW);  // 6 x 36864
    unsigned short* G2p = wprep + 6 * 36864;                     // 36864
    unsigned short* Fwp = G2p + 36864;                           // 16384
    unsigned short* zpad = Fwp + 16384;        // 64 shorts (zero page)
    unsigned short* B0 = zpad + 64;            // evblk
    unsigned short* B1 = B0 + NB;              // f0blk
    unsigned short* B2 = B1 + NB;              // t1blk
    unsigned short* B3 = B2 + NB;              // fusedblk -> fb2blk
    unsigned short* B4 = B3 + NB;              // hblk
    unsigned short* B5 = B4 + NB;              // fbblk (blocked f_blur)
    unsigned short* B6 = B5 + NB;              // s1blk

    // 0. weight preps + input blocking
    prep_w_k<<<dim3(144, 6), 256, 0, stream>>>(Wt1, Wt2, Wt3, G1, S1, S2, wprep);
    prep2_k<<<208, 256, 0, stream>>>(G2, Fw, G2p, Fwp, zpad);
    pre_blk_k<<<4096, 256, 0, stream>>>(f_event, f_blur, B0, B1, B5);
    // 1. L1: t1 = relu(conv(f0,Wt1)); h = relu(conv(ev,G1)+g1b); s1 = relu(conv(ev,S1))
    conv3x3_l1_blk<<<dim3(8, 8, 24), 256, 0, stream>>>(
        B1, B0, wprep + 0 * 36864, wprep + 3 * 36864, wprep + 4 * 36864, g1b,
        B2, B4, B6, zpad);
    // 2. L2: fused = conv(t1, Wt2); comp = chan-max/mean(conv(s1, S2))
    conv3x3_l2_blk<<<dim3(8, 8, 16), 256, 0, stream>>>(
        B2, B6, wprep + 1 * 36864, wprep + 5 * 36864, B3, comp, zpad);
    // 3. SE gate
    mean_hw_blk<<<Bn * 8, 256, 0, stream>>>(B3, w0);
    mlp_k<<<Bn, 128, 0, stream>>>(w0, A1, b1, A2, b2, w0s);
    // 4. merged: rgb gate conv (z<8) + scale_e = sigmoid(conv5x5(comp)) (z>=8)
    rgb_sconv_k<<<dim3(8, 8, 16), 256, 0, stream>>>(
        B3, wprep + 2 * 36864, Rw, rb, rgb, comp, Ew, eb, scale, zpad);
    // 5. fb2 = fb1 + dynconv(fb1, kern(h)), fb1 gating fused into staging
    dynfused_k<<<dim3(8, 16, Bn), 256, 0, stream>>>(B5, B4, G2p, g2b, w0s, rgb, B3);
    // 6. out = Fw @ concat(ev*(1+scale_e), fb2)
    fuse_mfma_k<<<Bn * HW / 128, 256, 0, stream>>>(B0, scale, B3, Fwp, out);
}

// Round 18
// 208.632 us; speedup vs baseline: 1.1134x; 1.0487x over previous
//
#include <hip/hip_runtime.h>
#include <math.h>

constexpr int Bn = 8, Cn = 64, Hn = 128, Wn = 128;
constexpr int HW  = Hn * Wn;      // 16384
constexpr int CHW = Cn * HW;      // 1048576
constexpr size_t NB = (size_t)Bn * CHW;   // elems per blocked tensor

typedef float  f32x4  __attribute__((ext_vector_type(4)));
typedef __bf16 bf16x8 __attribute__((ext_vector_type(8)));
typedef unsigned int u32x4 __attribute__((ext_vector_type(4)));
typedef unsigned int u32x2 __attribute__((ext_vector_type(2)));

static __device__ __forceinline__ unsigned short f2bf(float f) {
    unsigned u = __builtin_bit_cast(unsigned, f);
    u = (u + 0x7FFF + ((u >> 16) & 1)) >> 16;
    return (unsigned short)u;
}
static __device__ __forceinline__ float bf2f(unsigned short v) {
    unsigned u = (unsigned)v << 16;
    return __builtin_bit_cast(float, u);
}
static __device__ __forceinline__ float bfhalf(unsigned u, int hi) {
    unsigned r = hi ? (u & 0xffff0000u) : (u << 16);
    return __builtin_bit_cast(float, r);
}

// async global->LDS 16B (direct-to-shared); falls back to reg copy if unavailable
static __device__ __forceinline__ void gl_lds16(const unsigned short* g, unsigned short* l) {
#if defined(__has_builtin) && __has_builtin(__builtin_amdgcn_global_load_lds)
    __builtin_amdgcn_global_load_lds(
        (const __attribute__((address_space(1))) void*)g,
        (__attribute__((address_space(3))) void*)l, 16, 0, 0);
#else
    *(u32x4*)l = *(const u32x4*)g;
#endif
}

// ---------------- weight prep: OIHW fp32 -> [kk][s][t][co][8cj] bf16 ----------------
__global__ void prep_w_k(const float* __restrict__ W0, const float* __restrict__ W1,
                         const float* __restrict__ W2, const float* __restrict__ W3,
                         const float* __restrict__ W4, const float* __restrict__ W5,
                         unsigned short* __restrict__ dst) {
    int i = blockIdx.x * 256 + threadIdx.x;
    if (i >= 36864) return;
    const float* W = W0;
    switch (blockIdx.y) {
        case 1: W = W1; break; case 2: W = W2; break;
        case 3: W = W3; break; case 4: W = W4; break; case 5: W = W5; break;
        default: break;
    }
    int cj = i & 7;
    int rest = i >> 3;
    int co = rest & 63;
    rest >>= 6;              // (kk*4+s)*9 + t
    int t  = rest % 9;
    int hs = rest / 9;       // 0..7
    int ci = hs * 8 + cj;
    dst[(size_t)blockIdx.y * 36864 + i] = f2bf(W[(co * 64 + ci) * 9 + t]);
}

// ---------------- prep2: G2/Fw -> bf16; zero-page init ----------------
__global__ void prep2_k(const float* __restrict__ G2, const float* __restrict__ Fw,
                        unsigned short* __restrict__ G2p, unsigned short* __restrict__ Fwp,
                        unsigned short* __restrict__ zp) {
    int i = blockIdx.x * 256 + threadIdx.x;
    if (i < 64) zp[i] = 0;
    if (i < 36864) G2p[i] = f2bf(G2[i]);
    else if (i < 36864 + 16384) Fwp[i - 36864] = f2bf(Fw[i - 36864]);
}

// ---------------- pre: blocked bf16 of f_event, f_event+f_blur, f_blur ----------
__global__ void pre_blk_k(const float* __restrict__ fe, const float* __restrict__ fb,
                          unsigned short* __restrict__ evb, unsigned short* __restrict__ f0b,
                          unsigned short* __restrict__ fbb) {
    int i = blockIdx.x * 256 + threadIdx.x;       // (b, oct, px)
    int px = i & 16383;
    int oct = (i >> 14) & 7;
    int b = i >> 17;
    const float* pe = fe + (size_t)b * CHW + (size_t)oct * 8 * HW + px;
    const float* pb = fb + (size_t)b * CHW + (size_t)oct * 8 * HW + px;
    u32x4 ev, f0, fbv;
#pragma unroll
    for (int q = 0; q < 4; ++q) {
        float e0 = pe[(size_t)(2 * q) * HW],     b0 = pb[(size_t)(2 * q) * HW];
        float e1 = pe[(size_t)(2 * q + 1) * HW], b1 = pb[(size_t)(2 * q + 1) * HW];
        ev[q]  = (unsigned)f2bf(e0) | ((unsigned)f2bf(e1) << 16);
        f0[q]  = (unsigned)f2bf(e0 + b0) | ((unsigned)f2bf(e1 + b1) << 16);
        fbv[q] = (unsigned)f2bf(b0) | ((unsigned)f2bf(b1) << 16);
    }
    const size_t o = ((size_t)(b * 8 + oct) * HW + px) * 8;
    *(u32x4*)(evb + o) = ev;
    *(u32x4*)(f0b + o) = f0;
    *(u32x4*)(fbb + o) = fbv;
}

// ---------------- L1: three independent RELU convs in one launch -------------------
__global__ __launch_bounds__(256, 3) void conv3x3_l1_blk(
        const unsigned short* __restrict__ f0, const unsigned short* __restrict__ ev,
        const unsigned short* __restrict__ Wt1g, const unsigned short* __restrict__ G1g,
        const unsigned short* __restrict__ S1g, const float* __restrict__ g1b,
        unsigned short* __restrict__ out_t1, unsigned short* __restrict__ out_h,
        unsigned short* __restrict__ out_s1, const unsigned short* __restrict__ zp) {
    __shared__ unsigned short smIn[20736];
    const int z = blockIdx.z;
    const int b = z & 7, sel = z >> 3;
    const unsigned short* in = (sel == 0) ? f0 : ev;
    const unsigned short* Wg = (sel == 0) ? Wt1g : ((sel == 1) ? G1g : S1g);
    unsigned short* out = (sel == 0) ? out_t1 : ((sel == 1) ? out_h : out_s1);
    const int by = blockIdx.y << 4, bx = blockIdx.x << 4;
    const int tid = threadIdx.x;
    const int lane = tid & 63, w = tid >> 6;
    const int lx = lane & 15, ls = lane >> 4;

    for (int idx = tid; idx < 2592; idx += 256) {
        int oct = idx / 324;
        int p   = idx - oct * 324;
        int yy = p / 18, xx = p - yy * 18;
        int gy = by + yy - 1, gx = bx + xx - 1;
        const unsigned short* src =
            ((unsigned)gy < (unsigned)Hn && (unsigned)gx < (unsigned)Wn)
            ? in + ((size_t)(b * 8 + oct) * HW + gy * Wn + gx) * 8 : zp;
        gl_lds16(src, smIn + idx * 8);
    }
    __syncthreads();

    f32x4 acc[4][4];
#pragma unroll
    for (int m = 0; m < 4; ++m)
#pragma unroll
        for (int n = 0; n < 4; ++n) acc[m][n] = f32x4{0.f, 0.f, 0.f, 0.f};

#pragma unroll
    for (int ky = 0; ky < 3; ++ky)
#pragma unroll
    for (int kx = 0; kx < 3; ++kx) {
        const int t = ky * 3 + kx;
#pragma unroll
        for (int kk = 0; kk < 2; ++kk) {
            bf16x8 a[4];
            const unsigned short* wbase = Wg + kk * 18432 + ls * 4608 + t * 512 + lx * 8;
#pragma unroll
            for (int m = 0; m < 4; ++m)
                a[m] = *(const bf16x8*)(wbase + m * 128);
            const unsigned short* ibase =
                smIn + ((kk * 4 + ls) * 324 + (4 * w + ky) * 18 + lx + kx) * 8;
#pragma unroll
            for (int n = 0; n < 4; ++n) {
                bf16x8 bf = *(const bf16x8*)(ibase + n * 144);
#pragma unroll
                for (int m = 0; m < 4; ++m)
                    acc[m][n] = __builtin_amdgcn_mfma_f32_16x16x32_bf16(
                        a[m], bf, acc[m][n], 0, 0, 0);
            }
        }
    }

    const int y0 = by + 4 * w;
#pragma unroll
    for (int m = 0; m < 4; ++m) {
        float bv[4] = {0.f, 0.f, 0.f, 0.f};
        if (sel == 1) {
            float4 b4 = *(const float4*)(g1b + 16 * m + ls * 4);
            bv[0] = b4.x; bv[1] = b4.y; bv[2] = b4.z; bv[3] = b4.w;
        }
        const size_t rowb = (size_t)(b * 8 + m * 2 + (ls >> 1)) * HW;
        const int j0 = (ls & 1) * 4;
#pragma unroll
        for (int n = 0; n < 4; ++n) {
            const size_t pofs = rowb + (size_t)(y0 + n) * Wn + bx + lx;
            float vr[4];
#pragma unroll
            for (int r = 0; r < 4; ++r)
                vr[r] = fmaxf(acc[m][n][r] + bv[r], 0.f);
            u32x2 pk;
            pk[0] = (unsigned)f2bf(vr[0]) | ((unsigned)f2bf(vr[1]) << 16);
            pk[1] = (unsigned)f2bf(vr[2]) | ((unsigned)f2bf(vr[3]) << 16);
            *(u32x2*)(out + pofs * 8 + j0) = pk;
        }
    }
}

// ---------------- L2: Wt2 conv (store) + S2 conv (COMP epilogue) -------------------
__global__ __launch_bounds__(256, 3) void conv3x3_l2_blk(
        const unsigned short* __restrict__ t1, const unsigned short* __restrict__ s1,
        const unsigned short* __restrict__ Wt2g, const unsigned short* __restrict__ S2g,
        unsigned short* __restrict__ out_f, float* __restrict__ comp,
        const unsigned short* __restrict__ zp) {
    __shared__ unsigned short smIn[20736];
    const int z = blockIdx.z;
    const int b = z & 7, sel = z >> 3;
    const unsigned short* in = (sel == 0) ? t1 : s1;
    const unsigned short* Wg = (sel == 0) ? Wt2g : S2g;
    const int by = blockIdx.y << 4, bx = blockIdx.x << 4;
    const int tid = threadIdx.x;
    const int lane = tid & 63, w = tid >> 6;
    const int lx = lane & 15, ls = lane >> 4;

    for (int idx = tid; idx < 2592; idx += 256) {
        int oct = idx / 324;
        int p   = idx - oct * 324;
        int yy = p / 18, xx = p - yy * 18;
        int gy = by + yy - 1, gx = bx + xx - 1;
        const unsigned short* src =
            ((unsigned)gy < (unsigned)Hn && (unsigned)gx < (unsigned)Wn)
            ? in + ((size_t)(b * 8 + oct) * HW + gy * Wn + gx) * 8 : zp;
        gl_lds16(src, smIn + idx * 8);
    }
    __syncthreads();

    f32x4 acc[4][4];
#pragma unroll
    for (int m = 0; m < 4; ++m)
#pragma unroll
        for (int n = 0; n < 4; ++n) acc[m][n] = f32x4{0.f, 0.f, 0.f, 0.f};

#pragma unroll
    for (int ky = 0; ky < 3; ++ky)
#pragma unroll
    for (int kx = 0; kx < 3; ++kx) {
        const int t = ky * 3 + kx;
#pragma unroll
        for (int kk = 0; kk < 2; ++kk) {
            bf16x8 a[4];
            const unsigned short* wbase = Wg + kk * 18432 + ls * 4608 + t * 512 + lx * 8;
#pragma unroll
            for (int m = 0; m < 4; ++m)
                a[m] = *(const bf16x8*)(wbase + m * 128);
            const unsigned short* ibase =
                smIn + ((kk * 4 + ls) * 324 + (4 * w + ky) * 18 + lx + kx) * 8;
#pragma unroll
            for (int n = 0; n < 4; ++n) {
                bf16x8 bf = *(const bf16x8*)(ibase + n * 144);
#pragma unroll
                for (int m = 0; m < 4; ++m)
                    acc[m][n] = __builtin_amdgcn_mfma_f32_16x16x32_bf16(
                        a[m], bf, acc[m][n], 0, 0, 0);
            }
        }
    }

    const int y0 = by + 4 * w;
    if (sel == 0) {
#pragma unroll
        for (int m = 0; m < 4; ++m) {
            const size_t rowb = (size_t)(b * 8 + m * 2 + (ls >> 1)) * HW;
            const int j0 = (ls & 1) * 4;
#pragma unroll
            for (int n = 0; n < 4; ++n) {
                const size_t pofs = rowb + (size_t)(y0 + n) * Wn + bx + lx;
                u32x2 pk;
                pk[0] = (unsigned)f2bf(acc[m][n][0]) | ((unsigned)f2bf(acc[m][n][1]) << 16);
                pk[1] = (unsigned)f2bf(acc[m][n][2]) | ((unsigned)f2bf(acc[m][n][3]) << 16);
                *(u32x2*)(out_f + pofs * 8 + j0) = pk;
            }
        }
    } else {
        float gs[4], gm[4];
#pragma unroll
        for (int n = 0; n < 4; ++n) { gs[n] = 0.f; gm[n] = -1e30f; }
#pragma unroll
        for (int m = 0; m < 4; ++m)
#pragma unroll
            for (int r = 0; r < 4; ++r)
#pragma unroll
                for (int n = 0; n < 4; ++n) {
                    float v = acc[m][n][r];
                    gm[n] = fmaxf(gm[n], v);
                    gs[n] += v;
                }
#pragma unroll
        for (int n = 0; n < 4; ++n) {
            float s = gs[n], mx = gm[n];
            s += __shfl_xor(s, 16);
            s += __shfl_xor(s, 32);
            mx = fmaxf(mx, __shfl_xor(mx, 16));
            mx = fmaxf(mx, __shfl_xor(mx, 32));
            if (ls == 0) {
                const size_t o = (size_t)b * 2 * HW + (size_t)(y0 + n) * Wn + bx + lx;
                comp[o]      = mx;
                comp[o + HW] = s * (1.f / 64.f);
            }
        }
    }
}

// ---------------- merged: rgb-gate conv (z<8) + sconv5 (z>=8) ----------------------
__global__ __launch_bounds__(256, 3) void rgb_sconv_k(
        const unsigned short* __restrict__ in, const unsigned short* __restrict__ Wg,
        const float* __restrict__ gw, const float* __restrict__ gb,
        float* __restrict__ gout,
        const float* __restrict__ comp, const float* __restrict__ Ew,
        const float* __restrict__ eb, float* __restrict__ scale,
        const unsigned short* __restrict__ zp) {
    __shared__ unsigned short smIn[20736];
    const int z = blockIdx.z;
    if (z >= 8) {
        int id = (((z - 8) * 64) + blockIdx.y * 8 + blockIdx.x) * 256 + threadIdx.x;
        int sb = id >> 14, p = id & 16383;
        int y = p >> 7, x = p & 127;
        const float* cb = comp + (size_t)sb * 2 * HW;
        float sacc = eb[0];
#pragma unroll
        for (int ch = 0; ch < 2; ++ch)
#pragma unroll
            for (int ky = 0; ky < 5; ++ky) {
                int gy = y + ky - 2;
                if ((unsigned)gy >= (unsigned)Hn) continue;
#pragma unroll
                for (int kx = 0; kx < 5; ++kx) {
                    int gx = x + kx - 2;
                    if ((unsigned)gx >= (unsigned)Wn) continue;
                    sacc = fmaf(Ew[ch * 25 + ky * 5 + kx], cb[ch * HW + gy * Wn + gx], sacc);
                }
            }
        scale[id] = 1.f / (1.f + expf(-sacc));
        return;
    }
    const int b = z;
    const int by = blockIdx.y << 4, bx = blockIdx.x << 4;
    const int tid = threadIdx.x;
    const int lane = tid & 63, w = tid >> 6;
    const int lx = lane & 15, ls = lane >> 4;

    for (int idx = tid; idx < 2592; idx += 256) {
        int oct = idx / 324;
        int p   = idx - oct * 324;
        int yy = p / 18, xx = p - yy * 18;
        int gy = by + yy - 1, gx = bx + xx - 1;
        const unsigned short* src =
            ((unsigned)gy < (unsigned)Hn && (unsigned)gx < (unsigned)Wn)
            ? in + ((size_t)(b * 8 + oct) * HW + gy * Wn + gx) * 8 : zp;
        gl_lds16(src, smIn + idx * 8);
    }
    __syncthreads();

    f32x4 acc[4][4];
#pragma unroll
    for (int m = 0; m < 4; ++m)
#pragma unroll
        for (int n = 0; n < 4; ++n) acc[m][n] = f32x4{0.f, 0.f, 0.f, 0.f};

#pragma unroll
    for (int ky = 0; ky < 3; ++ky)
#pragma unroll
    for (int kx = 0; kx < 3; ++kx) {
        const int t = ky * 3 + kx;
#pragma unroll
        for (int kk = 0; kk < 2; ++kk) {
            bf16x8 a[4];
            const unsigned short* wbase = Wg + kk * 18432 + ls * 4608 + t * 512 + lx * 8;
#pragma unroll
            for (int m = 0; m < 4; ++m)
                a[m] = *(const bf16x8*)(wbase + m * 128);
            const unsigned short* ibase =
                smIn + ((kk * 4 + ls) * 324 + (4 * w + ky) * 18 + lx + kx) * 8;
#pragma unroll
            for (int n = 0; n < 4; ++n) {
                bf16x8 bf = *(const bf16x8*)(ibase + n * 144);
#pragma unroll
                for (int m = 0; m < 4; ++m)
                    acc[m][n] = __builtin_amdgcn_mfma_f32_16x16x32_bf16(
                        a[m], bf, acc[m][n], 0, 0, 0);
            }
        }
    }

    // epilogue: fused2 = in + relu(conv); rgb = sum_c gw[c]*fused2 + gb
    const int y0 = by + 4 * w;
    float gs[4];
#pragma unroll
    for (int n = 0; n < 4; ++n) gs[n] = 0.f;
#pragma unroll
    for (int m = 0; m < 4; ++m) {
        float4 rw4 = *(const float4*)(gw + 16 * m + ls * 4);
        const float rwf[4] = {rw4.x, rw4.y, rw4.z, rw4.w};
        const size_t rowb = (size_t)(b * 8 + m * 2 + (ls >> 1)) * HW;
        const int j0 = (ls & 1) * 4;
#pragma unroll
        for (int n = 0; n < 4; ++n) {
            const size_t pofs = rowb + (size_t)(y0 + n) * Wn + bx + lx;
            u32x2 rin = *(const u32x2*)(in + pofs * 8 + j0);
#pragma unroll
            for (int r = 0; r < 4; ++r) {
                float v = fmaxf(acc[m][n][r], 0.f) + bfhalf(rin[r >> 1], r & 1);
                gs[n] = fmaf(rwf[r], v, gs[n]);
            }
        }
    }
#pragma unroll
    for (int n = 0; n < 4; ++n) {
        float s = gs[n];
        s += __shfl_xor(s, 16);
        s += __shfl_xor(s, 32);
        if (ls == 0)
            gout[(size_t)b * HW + (size_t)(y0 + n) * Wn + bx + lx] = s + gb[0];
    }
}

// ---------------- mean over H,W per (b,oct) from blocked bf16 ----------------
__global__ void mean_hw_blk(const unsigned short* __restrict__ in, float* __restrict__ w0) {
    __shared__ float red[256][8];
    const int bo = blockIdx.x;                 // b*8+oct
    const int tid = threadIdx.x;
    const unsigned short* p = in + (size_t)bo * HW * 8;
    float s[8];
#pragma unroll
    for (int j = 0; j < 8; ++j) s[j] = 0.f;
    for (int it = 0; it < 64; ++it) {
        u32x4 v = *(const u32x4*)(p + (size_t)(tid + it * 256) * 8);
#pragma unroll
        for (int j = 0; j < 8; ++j) s[j] += bfhalf(v[j >> 1], j & 1);
    }
#pragma unroll
    for (int j = 0; j < 8; ++j) red[tid][j] = s[j];
    __syncthreads();
    for (int off = 128; off > 0; off >>= 1) {
        if (tid < off)
#pragma unroll
            for (int j = 0; j < 8; ++j) red[tid][j] += red[tid + off][j];
        __syncthreads();
    }
    if (tid < 8) w0[bo * 8 + tid] = red[0][tid] * (1.f / 16384.f);
}

// ---------------- SE MLP ----------------
__global__ void mlp_k(const float* __restrict__ w0, const float* __restrict__ A1,
                      const float* __restrict__ b1, const float* __restrict__ A2,
                      const float* __restrict__ b2, float* __restrict__ w0s) {
    int b = blockIdx.x, t = threadIdx.x;       // 128 threads
    __shared__ float w0r[64], hid[128];
    if (t < 64) w0r[t] = w0[b * 64 + t];
    __syncthreads();
    float s = b1[t];
    for (int c = 0; c < 64; ++c) s = fmaf(A1[t * 64 + c], w0r[c], s);
    hid[t] = fmaxf(s, 0.f);
    __syncthreads();
    if (t < 64) {
        float s2 = b2[t];
        for (int j = 0; j < 128; ++j) s2 = fmaf(A2[t * 128 + j], hid[j], s2);
        w0s[b * 64 + t] = 1.f / (1.f + expf(-s2));
    }
}

// ---------------- fused dynamic conv + final 1x1 fusion (out written here) ---------
// LDS union smA[19712]: [0..8192) = smU (h staging -> kern -> ev half of smF),
// [8192..19712) = smFB ([c64][180] gated patch -> fb2 half of smF at [8192..16384)).
__global__ __launch_bounds__(256, 4) void dynfused_k(
        const unsigned short* __restrict__ fbb, const unsigned short* __restrict__ hb,
        const unsigned short* __restrict__ G2p, const float* __restrict__ g2b,
        const float* __restrict__ w0s, const float* __restrict__ rgb,
        const unsigned short* __restrict__ evb, const float* __restrict__ scale,
        const unsigned short* __restrict__ Fwp, float* __restrict__ out) {
    __shared__ __align__(16) unsigned short smA[19712];
    unsigned short* smU  = smA;            // 8192 shorts
    unsigned short* smFB = smA + 8192;     // 11520 shorts
    const int b  = blockIdx.z;
    const int by = blockIdx.y << 3, bx = blockIdx.x << 4;
    const int tid = threadIdx.x;
    const int lane = tid & 63, w = tid >> 6;
    const int lx = lane & 15, ls = lane >> 4;
    const int wr = w & 1, wc = w >> 1;
    const int px = tid & 127;
    const int chalf = __builtin_amdgcn_readfirstlane(tid >> 7);  // wave-uniform
    const int ty = px >> 4, tx = px & 15;

    // stage h: async direct-to-LDS -> smU [oct][px][8]
#pragma unroll
    for (int it = 0; it < 4; ++it) {
        int i = tid + it * 256;
        int p = i & 127, oct = i >> 7;
        gl_lds16(hb + ((size_t)(b * 8 + oct) * HW + (by + (p >> 4)) * Wn + bx + (p & 15)) * 8,
                 smU + i * 8);
    }
    // stage fb patch with fb1 gating: blocked b128 load, gate, scatter to [c][180]
    const float* rgbb = rgb + (size_t)b * HW;
    for (int i = tid; i < 1440; i += 256) {
        int oct = i / 180, p = i - oct * 180;
        int pr = p / 18, pc = p - pr * 18;
        int gy = min(max(by + pr - 1, 0), Hn - 1);
        int gx = min(max(bx + pc - 1, 0), Wn - 1);
        u32x4 v = *(const u32x4*)(fbb + ((size_t)(b * 8 + oct) * HW + gy * Wn + gx) * 8);
        float g = 1.f + rgbb[gy * Wn + gx];
        float4 s0 = *(const float4*)(w0s + b * 64 + oct * 8);
        float4 s1 = *(const float4*)(w0s + b * 64 + oct * 8 + 4);
        const float sc[8] = {1.f + s0.x, 1.f + s0.y, 1.f + s0.z, 1.f + s0.w,
                             1.f + s1.x, 1.f + s1.y, 1.f + s1.z, 1.f + s1.w};
#pragma unroll
        for (int j = 0; j < 8; ++j)
            smFB[(oct * 8 + j) * 180 + p] = f2bf(bfhalf(v[j >> 1], j & 1) * sc[j] * g);
    }
    __syncthreads();

    // hoist b-frags (chunk-invariant) from smU to registers
    bf16x8 bv[2][4];
#pragma unroll
    for (int kk = 0; kk < 2; ++kk)
#pragma unroll
        for (int n = 0; n < 4; ++n)
            bv[kk][n] = *(const bf16x8*)(smU + ((kk * 4 + ls) * 128 + wc * 64 + n * 16 + lx) * 8);
    __syncthreads();                           // all reads done before smU becomes kern

    float acc[32];
#pragma unroll
    for (int s = 0; s < 32; ++s) acc[s] = 0.f;

#pragma unroll
    for (int chunk = 0; chunk < 9; ++chunk) {
        // GEMM: rows chunk*64 + wr*32 + [0,32), px wc*64 + [0,64), K=64
        f32x4 ka[2][4];
#pragma unroll
        for (int m = 0; m < 2; ++m)
#pragma unroll
            for (int n = 0; n < 4; ++n) ka[m][n] = f32x4{0.f, 0.f, 0.f, 0.f};
#pragma unroll
        for (int kk = 0; kk < 2; ++kk) {
            bf16x8 a[2];
#pragma unroll
            for (int m = 0; m < 2; ++m)
                a[m] = *(const bf16x8*)(G2p +
                        (size_t)(chunk * 64 + wr * 32 + m * 16 + lx) * 64 + kk * 32 + ls * 8);
#pragma unroll
            for (int n = 0; n < 4; ++n)
#pragma unroll
                for (int m = 0; m < 2; ++m)
                    ka[m][n] = __builtin_amdgcn_mfma_f32_16x16x32_bf16(a[m], bv[kk][n], ka[m][n], 0, 0, 0);
        }
        // epilogue: + g2b, write kern TRANSPOSED [pxl][rl] with 16B-granule XOR swizzle
#pragma unroll
        for (int m = 0; m < 2; ++m) {
            const float4 bb4 = *(const float4*)(g2b + chunk * 64 + wr * 32 + m * 16 + ls * 4);
            const float bb[4] = {bb4.x, bb4.y, bb4.z, bb4.w};
            const int rl0 = wr * 32 + m * 16 + ls * 4;   // multiple of 4
            const int gr = rl0 >> 3, sub = rl0 & 7;      // sub in {0,4}
#pragma unroll
            for (int n = 0; n < 4; ++n) {
                const int pxl = wc * 64 + n * 16 + lx;
                u32x2 pk;
                pk[0] = (unsigned)f2bf(ka[m][n][0] + bb[0]) |
                        ((unsigned)f2bf(ka[m][n][1] + bb[1]) << 16);
                pk[1] = (unsigned)f2bf(ka[m][n][2] + bb[2]) |
                        ((unsigned)f2bf(ka[m][n][3] + bb[3]) << 16);
                *(u32x2*)(smU + pxl * 64 + ((gr ^ (pxl & 7)) << 3) + sub) = pk;
            }
        }
        __syncthreads();
        // load own px column: all 64 rows as 8 b128
        u32x4 kvr[8];
#pragma unroll
        for (int k = 0; k < 8; ++k)
            kvr[k] = *(const u32x4*)(smU + px * 64 + ((k ^ (px & 7)) << 3));
        __syncthreads();                       // kvr done -> smU free; apply overlaps next GEMM
        // apply: rows of this chunk whose channel parity == chalf (c,t compile-time)
#pragma unroll
        for (int rl = 0; rl < 64; ++rl) {
            const int r = chunk * 64 + rl;         // compile-time
            const int c = r / 9, t = r - c * 9;    // compile-time
            const int s = c >> 1;
            if ((c & 1) == chalf) {
                float kv = bfhalf(kvr[rl >> 3][(rl & 7) >> 1], rl & 1);
                float pv = bf2f(smFB[c * 180 + (ty + t / 3) * 18 + tx + (t % 3)]);
                acc[s] = fmaf(kv, pv, acc[s]);
            }
        }
    }

    // ---- fused final 1x1: out = Fw @ concat(ev*(1+sc), fb2) for this 128-px tile ----
    // residual into acc (last smFB reads)
#pragma unroll
    for (int s = 0; s < 32; ++s) {
        const int c = 2 * s + chalf;
        acc[s] += bf2f(smFB[c * 180 + (ty + 1) * 18 + (tx + 1)]);
    }
    __syncthreads();                           // all smFB/smU reads done; smA reusable as smF
    // fb2 -> smA octs 8..15: [(8+(c>>3))*128 + px][8] + (c&7)
#pragma unroll
    for (int s = 0; s < 32; ++s) {
        const int c = 2 * s + chalf;
        smA[((8 + (c >> 3)) * 128 + px) * 8 + (c & 7)] = f2bf(acc[s]);
    }
    // ev*(1+scale_e) -> smA octs 0..7
#pragma unroll
    for (int it = 0; it < 4; ++it) {
        int i = tid + it * 256;
        int p = i & 127, oct = i >> 7;
        int gy = by + (p >> 4), gx = bx + (p & 15);
        u32x4 v = *(const u32x4*)(evb + ((size_t)(b * 8 + oct) * HW + gy * Wn + gx) * 8);
        float sv = 1.f + scale[(size_t)b * HW + gy * Wn + gx];
#pragma unroll
        for (int q = 0; q < 4; ++q)
            v[q] = (unsigned)f2bf(bfhalf(v[q], 0) * sv) |
                   ((unsigned)f2bf(bfhalf(v[q], 1) * sv) << 16);
        *(u32x4*)(smA + (oct * 128 + p) * 8) = v;
    }
    __syncthreads();

    // GEMM: 128 co x 128 px, K=128; m split in halves for register pressure
    const size_t ob = (size_t)b * 2 * CHW;
#pragma unroll
    for (int mh = 0; mh < 2; ++mh) {
        f32x4 a2[2][4];
#pragma unroll
        for (int m = 0; m < 2; ++m)
#pragma unroll
            for (int n = 0; n < 4; ++n) a2[m][n] = f32x4{0.f, 0.f, 0.f, 0.f};
#pragma unroll
        for (int kk = 0; kk < 4; ++kk) {
            bf16x8 af[2];
#pragma unroll
            for (int m = 0; m < 2; ++m)
                af[m] = *(const bf16x8*)(Fwp +
                        (size_t)(wr * 64 + mh * 32 + m * 16 + lx) * 128 + kk * 32 + ls * 8);
#pragma unroll
            for (int n = 0; n < 4; ++n) {
                bf16x8 bvv = *(const bf16x8*)(smA + ((kk * 4 + ls) * 128 + wc * 64 + n * 16 + lx) * 8);
#pragma unroll
                for (int m = 0; m < 2; ++m)
                    a2[m][n] = __builtin_amdgcn_mfma_f32_16x16x32_bf16(af[m], bvv, a2[m][n], 0, 0, 0);
            }
        }
#pragma unroll
        for (int m = 0; m < 2; ++m)
#pragma unroll
            for (int n = 0; n < 4; ++n) {
                const int pxl = wc * 64 + n * 16 + lx;
                const int gy = by + (pxl >> 4), gx = bx + (pxl & 15);
#pragma unroll
                for (int j = 0; j < 4; ++j) {
                    const int co = wr * 64 + mh * 32 + m * 16 + ls * 4 + j;
                    out[ob + (size_t)co * HW + (size_t)gy * Wn + gx] = a2[m][n][j];
                }
            }
    }
}

// ---------------- host launch ----------------
extern "C" void kernel_launch(void* const* d_in, const int* in_sizes, int n_in,
                              void* d_out, int out_size, void* d_ws, size_t ws_size,
                              hipStream_t stream) {
    const float* f_event = (const float*)d_in[0];
    const float* f_blur  = (const float*)d_in[1];
    const float* Wt1 = (const float*)d_in[2];
    const float* Wt2 = (const float*)d_in[3];
    const float* Wt3 = (const float*)d_in[4];
    const float* A1  = (const float*)d_in[5];
    const float* b1  = (const float*)d_in[6];
    const float* A2  = (const float*)d_in[7];
    const float* b2  = (const float*)d_in[8];
    const float* G1  = (const float*)d_in[9];
    const float* g1b = (const float*)d_in[10];
    const float* G2  = (const float*)d_in[11];
    const float* g2b = (const float*)d_in[12];
    const float* Rw  = (const float*)d_in[13];
    const float* rb  = (const float*)d_in[14];
    const float* S1  = (const float*)d_in[15];
    const float* S2  = (const float*)d_in[16];
    const float* Ew  = (const float*)d_in[17];
    const float* eb  = (const float*)d_in[18];
    const float* Fw  = (const float*)d_in[19];
    float* out = (float*)d_out;

    float* ws    = (float*)d_ws;
    float* w0    = ws;                         // 512
    float* w0s   = w0 + 512;                   // 512
    float* rgb   = w0s + 512;                  // 131072
    float* comp  = rgb + Bn * HW;              // 262144
    float* scale = comp + 2 * Bn * HW;         // 131072
    unsigned short* wprep = (unsigned short*)(scale + Bn * HW);  // 6 x 36864
    unsigned short* G2p = wprep + 6 * 36864;                     // 36864
    unsigned short* Fwp = G2p + 36864;                           // 16384
    unsigned short* zpad = Fwp + 16384;        // 64 shorts (zero page)
    unsigned short* B0 = zpad + 64;            // evblk
    unsigned short* B1 = B0 + NB;              // f0blk
    unsigned short* B2 = B1 + NB;              // t1blk
    unsigned short* B3 = B2 + NB;              // fusedblk
    unsigned short* B4 = B3 + NB;              // hblk
    unsigned short* B5 = B4 + NB;              // fbblk (blocked f_blur)
    unsigned short* B6 = B5 + NB;              // s1blk

    // 0. weight preps + input blocking
    prep_w_k<<<dim3(144, 6), 256, 0, stream>>>(Wt1, Wt2, Wt3, G1, S1, S2, wprep);
    prep2_k<<<208, 256, 0, stream>>>(G2, Fw, G2p, Fwp, zpad);
    pre_blk_k<<<4096, 256, 0, stream>>>(f_event, f_blur, B0, B1, B5);
    // 1. L1: t1 = relu(conv(f0,Wt1)); h = relu(conv(ev,G1)+g1b); s1 = relu(conv(ev,S1))
    conv3x3_l1_blk<<<dim3(8, 8, 24), 256, 0, stream>>>(
        B1, B0, wprep + 0 * 36864, wprep + 3 * 36864, wprep + 4 * 36864, g1b,
        B2, B4, B6, zpad);
    // 2. L2: fused = conv(t1, Wt2); comp = chan-max/mean(conv(s1, S2))
    conv3x3_l2_blk<<<dim3(8, 8, 16), 256, 0, stream>>>(
        B2, B6, wprep + 1 * 36864, wprep + 5 * 36864, B3, comp, zpad);
    // 3. SE gate
    mean_hw_blk<<<Bn * 8, 256, 0, stream>>>(B3, w0);
    mlp_k<<<Bn, 128, 0, stream>>>(w0, A1, b1, A2, b2, w0s);
    // 4. merged: rgb gate conv (z<8) + scale_e = sigmoid(conv5x5(comp)) (z>=8)
    rgb_sconv_k<<<dim3(8, 8, 16), 256, 0, stream>>>(
        B3, wprep + 2 * 36864, Rw, rb, rgb, comp, Ew, eb, scale, zpad);
    // 5. fb2 = fb1 + dynconv(fb1, kern(h)); then out = Fw @ concat(ev*(1+sc), fb2)
    dynfused_k<<<dim3(8, 16, Bn), 256, 0, stream>>>(
        B5, B4, G2p, g2b, w0s, rgb, B0, scale, Fwp, out);
}

// Round 19
// 195.623 us; speedup vs baseline: 1.1875x; 1.0665x over previous
//
#include <hip/hip_runtime.h>
#include <math.h>

constexpr int Bn = 8, Cn = 64, Hn = 128, Wn = 128;
constexpr int HW  = Hn * Wn;      // 16384
constexpr int CHW = Cn * HW;      // 1048576
constexpr size_t NB = (size_t)Bn * CHW;   // elems per blocked tensor

typedef float  f32x4  __attribute__((ext_vector_type(4)));
typedef __bf16 bf16x8 __attribute__((ext_vector_type(8)));
typedef unsigned int u32x4 __attribute__((ext_vector_type(4)));
typedef unsigned int u32x2 __attribute__((ext_vector_type(2)));

static __device__ __forceinline__ unsigned short f2bf(float f) {
    unsigned u = __builtin_bit_cast(unsigned, f);
    u = (u + 0x7FFF + ((u >> 16) & 1)) >> 16;
    return (unsigned short)u;
}
static __device__ __forceinline__ float bf2f(unsigned short v) {
    unsigned u = (unsigned)v << 16;
    return __builtin_bit_cast(float, u);
}
static __device__ __forceinline__ float bfhalf(unsigned u, int hi) {
    unsigned r = hi ? (u & 0xffff0000u) : (u << 16);
    return __builtin_bit_cast(float, r);
}

// async global->LDS 16B (direct-to-shared); falls back to reg copy if unavailable
static __device__ __forceinline__ void gl_lds16(const unsigned short* g, unsigned short* l) {
#if defined(__has_builtin) && __has_builtin(__builtin_amdgcn_global_load_lds)
    __builtin_amdgcn_global_load_lds(
        (const __attribute__((address_space(1))) void*)g,
        (__attribute__((address_space(3))) void*)l, 16, 0, 0);
#else
    *(u32x4*)l = *(const u32x4*)g;
#endif
}

// ---------------- merged prep: pre_blk (0..4095) | prep_w (4096..4959) | prep2 ----
__global__ void prep_all_k(const float* __restrict__ fe, const float* __restrict__ fb,
                           unsigned short* __restrict__ evb, unsigned short* __restrict__ f0b,
                           unsigned short* __restrict__ fbb,
                           const float* __restrict__ W0, const float* __restrict__ W1,
                           const float* __restrict__ W2, const float* __restrict__ W3,
                           const float* __restrict__ W4, const float* __restrict__ W5,
                           unsigned short* __restrict__ wdst,
                           const float* __restrict__ G2, const float* __restrict__ Fw,
                           unsigned short* __restrict__ G2p, unsigned short* __restrict__ Fwp,
                           unsigned short* __restrict__ zp) {
    const int blk = blockIdx.x;
    const int tid = threadIdx.x;
    if (blk < 4096) {
        // pre_blk: blocked bf16 of f_event, f_event+f_blur, f_blur
        int i = blk * 256 + tid;
        int px = i & 16383;
        int oct = (i >> 14) & 7;
        int b = i >> 17;
        const float* pe = fe + (size_t)b * CHW + (size_t)oct * 8 * HW + px;
        const float* pb = fb + (size_t)b * CHW + (size_t)oct * 8 * HW + px;
        u32x4 ev, f0, fbv;
#pragma unroll
        for (int q = 0; q < 4; ++q) {
            float e0 = pe[(size_t)(2 * q) * HW],     b0 = pb[(size_t)(2 * q) * HW];
            float e1 = pe[(size_t)(2 * q + 1) * HW], b1 = pb[(size_t)(2 * q + 1) * HW];
            ev[q]  = (unsigned)f2bf(e0) | ((unsigned)f2bf(e1) << 16);
            f0[q]  = (unsigned)f2bf(e0 + b0) | ((unsigned)f2bf(e1 + b1) << 16);
            fbv[q] = (unsigned)f2bf(b0) | ((unsigned)f2bf(b1) << 16);
        }
        const size_t o = ((size_t)(b * 8 + oct) * HW + px) * 8;
        *(u32x4*)(evb + o) = ev;
        *(u32x4*)(f0b + o) = f0;
        *(u32x4*)(fbb + o) = fbv;
    } else if (blk < 4960) {
        // prep_w: OIHW fp32 -> [kk][s][t][co][8cj] bf16, 6 weight sets
        int wblk = blk - 4096;
        int wi = wblk % 144, wy = wblk / 144;
        int i = wi * 256 + tid;
        if (i >= 36864) return;
        const float* W = W0;
        switch (wy) {
            case 1: W = W1; break; case 2: W = W2; break;
            case 3: W = W3; break; case 4: W = W4; break; case 5: W = W5; break;
            default: break;
        }
        int cj = i & 7;
        int rest = i >> 3;
        int co = rest & 63;
        rest >>= 6;
        int t  = rest % 9;
        int hs = rest / 9;
        int ci = hs * 8 + cj;
        wdst[(size_t)wy * 36864 + i] = f2bf(W[(co * 64 + ci) * 9 + t]);
    } else {
        // prep2: G2/Fw -> bf16; zero-page init
        int i = (blk - 4960) * 256 + tid;
        if (i < 64) zp[i] = 0;
        if (i < 36864) G2p[i] = f2bf(G2[i]);
        else if (i < 36864 + 16384) Fwp[i - 36864] = f2bf(Fw[i - 36864]);
    }
}

// ---------------- L1: three independent RELU convs in one launch -------------------
__global__ __launch_bounds__(256, 3) void conv3x3_l1_blk(
        const unsigned short* __restrict__ f0, const unsigned short* __restrict__ ev,
        const unsigned short* __restrict__ Wt1g, const unsigned short* __restrict__ G1g,
        const unsigned short* __restrict__ S1g, const float* __restrict__ g1b,
        unsigned short* __restrict__ out_t1, unsigned short* __restrict__ out_h,
        unsigned short* __restrict__ out_s1, const unsigned short* __restrict__ zp) {
    __shared__ unsigned short smIn[20736];
    const int z = blockIdx.z;
    const int b = z & 7, sel = z >> 3;
    const unsigned short* in = (sel == 0) ? f0 : ev;
    const unsigned short* Wg = (sel == 0) ? Wt1g : ((sel == 1) ? G1g : S1g);
    unsigned short* out = (sel == 0) ? out_t1 : ((sel == 1) ? out_h : out_s1);
    const int by = blockIdx.y << 4, bx = blockIdx.x << 4;
    const int tid = threadIdx.x;
    const int lane = tid & 63, w = tid >> 6;
    const int lx = lane & 15, ls = lane >> 4;

    for (int idx = tid; idx < 2592; idx += 256) {
        int oct = idx / 324;
        int p   = idx - oct * 324;
        int yy = p / 18, xx = p - yy * 18;
        int gy = by + yy - 1, gx = bx + xx - 1;
        const unsigned short* src =
            ((unsigned)gy < (unsigned)Hn && (unsigned)gx < (unsigned)Wn)
            ? in + ((size_t)(b * 8 + oct) * HW + gy * Wn + gx) * 8 : zp;
        gl_lds16(src, smIn + idx * 8);
    }
    __syncthreads();

    f32x4 acc[4][4];
#pragma unroll
    for (int m = 0; m < 4; ++m)
#pragma unroll
        for (int n = 0; n < 4; ++n) acc[m][n] = f32x4{0.f, 0.f, 0.f, 0.f};

#pragma unroll
    for (int ky = 0; ky < 3; ++ky)
#pragma unroll
    for (int kx = 0; kx < 3; ++kx) {
        const int t = ky * 3 + kx;
#pragma unroll
        for (int kk = 0; kk < 2; ++kk) {
            bf16x8 a[4];
            const unsigned short* wbase = Wg + kk * 18432 + ls * 4608 + t * 512 + lx * 8;
#pragma unroll
            for (int m = 0; m < 4; ++m)
                a[m] = *(const bf16x8*)(wbase + m * 128);
            const unsigned short* ibase =
                smIn + ((kk * 4 + ls) * 324 + (4 * w + ky) * 18 + lx + kx) * 8;
#pragma unroll
            for (int n = 0; n < 4; ++n) {
                bf16x8 bf = *(const bf16x8*)(ibase + n * 144);
#pragma unroll
                for (int m = 0; m < 4; ++m)
                    acc[m][n] = __builtin_amdgcn_mfma_f32_16x16x32_bf16(
                        a[m], bf, acc[m][n], 0, 0, 0);
            }
        }
    }

    const int y0 = by + 4 * w;
#pragma unroll
    for (int m = 0; m < 4; ++m) {
        float bv[4] = {0.f, 0.f, 0.f, 0.f};
        if (sel == 1) {
            float4 b4 = *(const float4*)(g1b + 16 * m + ls * 4);
            bv[0] = b4.x; bv[1] = b4.y; bv[2] = b4.z; bv[3] = b4.w;
        }
        const size_t rowb = (size_t)(b * 8 + m * 2 + (ls >> 1)) * HW;
        const int j0 = (ls & 1) * 4;
#pragma unroll
        for (int n = 0; n < 4; ++n) {
            const size_t pofs = rowb + (size_t)(y0 + n) * Wn + bx + lx;
            float vr[4];
#pragma unroll
            for (int r = 0; r < 4; ++r)
                vr[r] = fmaxf(acc[m][n][r] + bv[r], 0.f);
            u32x2 pk;
            pk[0] = (unsigned)f2bf(vr[0]) | ((unsigned)f2bf(vr[1]) << 16);
            pk[1] = (unsigned)f2bf(vr[2]) | ((unsigned)f2bf(vr[3]) << 16);
            *(u32x2*)(out + pofs * 8 + j0) = pk;
        }
    }
}

// ---------------- L2: Wt2 conv (store) + S2 conv (COMP epilogue) -------------------
__global__ __launch_bounds__(256, 3) void conv3x3_l2_blk(
        const unsigned short* __restrict__ t1, const unsigned short* __restrict__ s1,
        const unsigned short* __restrict__ Wt2g, const unsigned short* __restrict__ S2g,
        unsigned short* __restrict__ out_f, float* __restrict__ comp,
        const unsigned short* __restrict__ zp) {
    __shared__ unsigned short smIn[20736];
    const int z = blockIdx.z;
    const int b = z & 7, sel = z >> 3;
    const unsigned short* in = (sel == 0) ? t1 : s1;
    const unsigned short* Wg = (sel == 0) ? Wt2g : S2g;
    const int by = blockIdx.y << 4, bx = blockIdx.x << 4;
    const int tid = threadIdx.x;
    const int lane = tid & 63, w = tid >> 6;
    const int lx = lane & 15, ls = lane >> 4;

    for (int idx = tid; idx < 2592; idx += 256) {
        int oct = idx / 324;
        int p   = idx - oct * 324;
        int yy = p / 18, xx = p - yy * 18;
        int gy = by + yy - 1, gx = bx + xx - 1;
        const unsigned short* src =
            ((unsigned)gy < (unsigned)Hn && (unsigned)gx < (unsigned)Wn)
            ? in + ((size_t)(b * 8 + oct) * HW + gy * Wn + gx) * 8 : zp;
        gl_lds16(src, smIn + idx * 8);
    }
    __syncthreads();

    f32x4 acc[4][4];
#pragma unroll
    for (int m = 0; m < 4; ++m)
#pragma unroll
        for (int n = 0; n < 4; ++n) acc[m][n] = f32x4{0.f, 0.f, 0.f, 0.f};

#pragma unroll
    for (int ky = 0; ky < 3; ++ky)
#pragma unroll
    for (int kx = 0; kx < 3; ++kx) {
        const int t = ky * 3 + kx;
#pragma unroll
        for (int kk = 0; kk < 2; ++kk) {
            bf16x8 a[4];
            const unsigned short* wbase = Wg + kk * 18432 + ls * 4608 + t * 512 + lx * 8;
#pragma unroll
            for (int m = 0; m < 4; ++m)
                a[m] = *(const bf16x8*)(wbase + m * 128);
            const unsigned short* ibase =
                smIn + ((kk * 4 + ls) * 324 + (4 * w + ky) * 18 + lx + kx) * 8;
#pragma unroll
            for (int n = 0; n < 4; ++n) {
                bf16x8 bf = *(const bf16x8*)(ibase + n * 144);
#pragma unroll
                for (int m = 0; m < 4; ++m)
                    acc[m][n] = __builtin_amdgcn_mfma_f32_16x16x32_bf16(
                        a[m], bf, acc[m][n], 0, 0, 0);
            }
        }
    }

    const int y0 = by + 4 * w;
    if (sel == 0) {
#pragma unroll
        for (int m = 0; m < 4; ++m) {
            const size_t rowb = (size_t)(b * 8 + m * 2 + (ls >> 1)) * HW;
            const int j0 = (ls & 1) * 4;
#pragma unroll
            for (int n = 0; n < 4; ++n) {
                const size_t pofs = rowb + (size_t)(y0 + n) * Wn + bx + lx;
                u32x2 pk;
                pk[0] = (unsigned)f2bf(acc[m][n][0]) | ((unsigned)f2bf(acc[m][n][1]) << 16);
                pk[1] = (unsigned)f2bf(acc[m][n][2]) | ((unsigned)f2bf(acc[m][n][3]) << 16);
                *(u32x2*)(out_f + pofs * 8 + j0) = pk;
            }
        }
    } else {
        float gs[4], gm[4];
#pragma unroll
        for (int n = 0; n < 4; ++n) { gs[n] = 0.f; gm[n] = -1e30f; }
#pragma unroll
        for (int m = 0; m < 4; ++m)
#pragma unroll
            for (int r = 0; r < 4; ++r)
#pragma unroll
                for (int n = 0; n < 4; ++n) {
                    float v = acc[m][n][r];
                    gm[n] = fmaxf(gm[n], v);
                    gs[n] += v;
                }
#pragma unroll
        for (int n = 0; n < 4; ++n) {
            float s = gs[n], mx = gm[n];
            s += __shfl_xor(s, 16);
            s += __shfl_xor(s, 32);
            mx = fmaxf(mx, __shfl_xor(mx, 16));
            mx = fmaxf(mx, __shfl_xor(mx, 32));
            if (ls == 0) {
                const size_t o = (size_t)b * 2 * HW + (size_t)(y0 + n) * Wn + bx + lx;
                comp[o]      = mx;
                comp[o + HW] = s * (1.f / 64.f);
            }
        }
    }
}

// ---------------- merged: rgb conv (z<8) + sconv5 (8<=z<16) + SE MLP (z==16) -------
__global__ __launch_bounds__(256, 3) void rgb_sconv_mlp_k(
        const unsigned short* __restrict__ in, const unsigned short* __restrict__ Wg,
        const float* __restrict__ gw, const float* __restrict__ gb,
        float* __restrict__ gout,
        const float* __restrict__ comp, const float* __restrict__ Ew,
        const float* __restrict__ eb, float* __restrict__ scale,
        const unsigned short* __restrict__ zp,
        const float* __restrict__ w0, const float* __restrict__ A1,
        const float* __restrict__ b1, const float* __restrict__ A2,
        const float* __restrict__ b2, float* __restrict__ w0s) {
    __shared__ unsigned short smIn[20736];
    const int z = blockIdx.z;
    const int tid = threadIdx.x;
    if (z == 16) {
        // SE MLP: 8 useful blocks (y==0, x = batch)
        if (blockIdx.y != 0) return;
        const int b = blockIdx.x;
        float* w0r = (float*)smIn;             // 64 floats
        float* hid = w0r + 64;                 // 128 floats
        if (tid < 64) w0r[tid] = w0[b * 64 + tid];
        __syncthreads();
        float s = 0.f;
        if (tid < 128) {
            s = b1[tid];
            for (int c = 0; c < 64; ++c) s = fmaf(A1[tid * 64 + c], w0r[c], s);
        }
        if (tid < 128) hid[tid] = fmaxf(s, 0.f);
        __syncthreads();
        if (tid < 64) {
            float s2 = b2[tid];
            for (int j = 0; j < 128; ++j) s2 = fmaf(A2[tid * 128 + j], hid[j], s2);
            w0s[b * 64 + tid] = 1.f / (1.f + expf(-s2));
        }
        return;
    }
    if (z >= 8) {
        int id = (((z - 8) * 64) + blockIdx.y * 8 + blockIdx.x) * 256 + tid;
        int sb = id >> 14, p = id & 16383;
        int y = p >> 7, x = p & 127;
        const float* cb = comp + (size_t)sb * 2 * HW;
        float sacc = eb[0];
#pragma unroll
        for (int ch = 0; ch < 2; ++ch)
#pragma unroll
            for (int ky = 0; ky < 5; ++ky) {
                int gy = y + ky - 2;
                if ((unsigned)gy >= (unsigned)Hn) continue;
#pragma unroll
                for (int kx = 0; kx < 5; ++kx) {
                    int gx = x + kx - 2;
                    if ((unsigned)gx >= (unsigned)Wn) continue;
                    sacc = fmaf(Ew[ch * 25 + ky * 5 + kx], cb[ch * HW + gy * Wn + gx], sacc);
                }
            }
        scale[id] = 1.f / (1.f + expf(-sacc));
        return;
    }
    const int b = z;
    const int by = blockIdx.y << 4, bx = blockIdx.x << 4;
    const int lane = tid & 63, w = tid >> 6;
    const int lx = lane & 15, ls = lane >> 4;

    for (int idx = tid; idx < 2592; idx += 256) {
        int oct = idx / 324;
        int p   = idx - oct * 324;
        int yy = p / 18, xx = p - yy * 18;
        int gy = by + yy - 1, gx = bx + xx - 1;
        const unsigned short* src =
            ((unsigned)gy < (unsigned)Hn && (unsigned)gx < (unsigned)Wn)
            ? in + ((size_t)(b * 8 + oct) * HW + gy * Wn + gx) * 8 : zp;
        gl_lds16(src, smIn + idx * 8);
    }
    __syncthreads();

    f32x4 acc[4][4];
#pragma unroll
    for (int m = 0; m < 4; ++m)
#pragma unroll
        for (int n = 0; n < 4; ++n) acc[m][n] = f32x4{0.f, 0.f, 0.f, 0.f};

#pragma unroll
    for (int ky = 0; ky < 3; ++ky)
#pragma unroll
    for (int kx = 0; kx < 3; ++kx) {
        const int t = ky * 3 + kx;
#pragma unroll
        for (int kk = 0; kk < 2; ++kk) {
            bf16x8 a[4];
            const unsigned short* wbase = Wg + kk * 18432 + ls * 4608 + t * 512 + lx * 8;
#pragma unroll
            for (int m = 0; m < 4; ++m)
                a[m] = *(const bf16x8*)(wbase + m * 128);
            const unsigned short* ibase =
                smIn + ((kk * 4 + ls) * 324 + (4 * w + ky) * 18 + lx + kx) * 8;
#pragma unroll
            for (int n = 0; n < 4; ++n) {
                bf16x8 bf = *(const bf16x8*)(ibase + n * 144);
#pragma unroll
                for (int m = 0; m < 4; ++m)
                    acc[m][n] = __builtin_amdgcn_mfma_f32_16x16x32_bf16(
                        a[m], bf, acc[m][n], 0, 0, 0);
            }
        }
    }

    // epilogue: fused2 = in + relu(conv); rgb = sum_c gw[c]*fused2 + gb
    const int y0 = by + 4 * w;
    float gs[4];
#pragma unroll
    for (int n = 0; n < 4; ++n) gs[n] = 0.f;
#pragma unroll
    for (int m = 0; m < 4; ++m) {
        float4 rw4 = *(const float4*)(gw + 16 * m + ls * 4);
        const float rwf[4] = {rw4.x, rw4.y, rw4.z, rw4.w};
        const size_t rowb = (size_t)(b * 8 + m * 2 + (ls >> 1)) * HW;
        const int j0 = (ls & 1) * 4;
#pragma unroll
        for (int n = 0; n < 4; ++n) {
            const size_t pofs = rowb + (size_t)(y0 + n) * Wn + bx + lx;
            u32x2 rin = *(const u32x2*)(in + pofs * 8 + j0);
#pragma unroll
            for (int r = 0; r < 4; ++r) {
                float v = fmaxf(acc[m][n][r], 0.f) + bfhalf(rin[r >> 1], r & 1);
                gs[n] = fmaf(rwf[r], v, gs[n]);
            }
        }
    }
#pragma unroll
    for (int n = 0; n < 4; ++n) {
        float s = gs[n];
        s += __shfl_xor(s, 16);
        s += __shfl_xor(s, 32);
        if (ls == 0)
            gout[(size_t)b * HW + (size_t)(y0 + n) * Wn + bx + lx] = s + gb[0];
    }
}

// ---------------- mean over H,W per (b,oct) from blocked bf16 ----------------
__global__ void mean_hw_blk(const unsigned short* __restrict__ in, float* __restrict__ w0) {
    __shared__ float red[256][8];
    const int bo = blockIdx.x;                 // b*8+oct
    const int tid = threadIdx.x;
    const unsigned short* p = in + (size_t)bo * HW * 8;
    float s[8];
#pragma unroll
    for (int j = 0; j < 8; ++j) s[j] = 0.f;
    for (int it = 0; it < 64; ++it) {
        u32x4 v = *(const u32x4*)(p + (size_t)(tid + it * 256) * 8);
#pragma unroll
        for (int j = 0; j < 8; ++j) s[j] += bfhalf(v[j >> 1], j & 1);
    }
#pragma unroll
    for (int j = 0; j < 8; ++j) red[tid][j] = s[j];
    __syncthreads();
    for (int off = 128; off > 0; off >>= 1) {
        if (tid < off)
#pragma unroll
            for (int j = 0; j < 8; ++j) red[tid][j] += red[tid + off][j];
        __syncthreads();
    }
    if (tid < 8) w0[bo * 8 + tid] = red[0][tid] * (1.f / 16384.f);
}

// ---------------- fused dynamic conv + final 1x1 fusion (out written here) ---------
__global__ __launch_bounds__(256, 4) void dynfused_k(
        const unsigned short* __restrict__ fbb, const unsigned short* __restrict__ hb,
        const unsigned short* __restrict__ G2p, const float* __restrict__ g2b,
        const float* __restrict__ w0s, const float* __restrict__ rgb,
        const unsigned short* __restrict__ evb, const float* __restrict__ scale,
        const unsigned short* __restrict__ Fwp, float* __restrict__ out) {
    __shared__ __align__(16) unsigned short smA[19712];
    unsigned short* smU  = smA;            // 8192 shorts
    unsigned short* smFB = smA + 8192;     // 11520 shorts
    const int b  = blockIdx.z;
    const int by = blockIdx.y << 3, bx = blockIdx.x << 4;
    const int tid = threadIdx.x;
    const int lane = tid & 63, w = tid >> 6;
    const int lx = lane & 15, ls = lane >> 4;
    const int wr = w & 1, wc = w >> 1;
    const int px = tid & 127;
    const int chalf = __builtin_amdgcn_readfirstlane(tid >> 7);  // wave-uniform
    const int ty = px >> 4, tx = px & 15;

    // stage h: async direct-to-LDS -> smU [oct][px][8]
#pragma unroll
    for (int it = 0; it < 4; ++it) {
        int i = tid + it * 256;
        int p = i & 127, oct = i >> 7;
        gl_lds16(hb + ((size_t)(b * 8 + oct) * HW + (by + (p >> 4)) * Wn + bx + (p & 15)) * 8,
                 smU + i * 8);
    }
    // stage fb patch with fb1 gating: blocked b128 load, gate, scatter to [c][180]
    const float* rgbb = rgb + (size_t)b * HW;
    for (int i = tid; i < 1440; i += 256) {
        int oct = i / 180, p = i - oct * 180;
        int pr = p / 18, pc = p - pr * 18;
        int gy = min(max(by + pr - 1, 0), Hn - 1);
        int gx = min(max(bx + pc - 1, 0), Wn - 1);
        u32x4 v = *(const u32x4*)(fbb + ((size_t)(b * 8 + oct) * HW + gy * Wn + gx) * 8);
        float g = 1.f + rgbb[gy * Wn + gx];
        float4 s0 = *(const float4*)(w0s + b * 64 + oct * 8);
        float4 s1 = *(const float4*)(w0s + b * 64 + oct * 8 + 4);
        const float sc[8] = {1.f + s0.x, 1.f + s0.y, 1.f + s0.z, 1.f + s0.w,
                             1.f + s1.x, 1.f + s1.y, 1.f + s1.z, 1.f + s1.w};
#pragma unroll
        for (int j = 0; j < 8; ++j)
            smFB[(oct * 8 + j) * 180 + p] = f2bf(bfhalf(v[j >> 1], j & 1) * sc[j] * g);
    }
    __syncthreads();

    // hoist b-frags (chunk-invariant) from smU to registers
    bf16x8 bv[2][4];
#pragma unroll
    for (int kk = 0; kk < 2; ++kk)
#pragma unroll
        for (int n = 0; n < 4; ++n)
            bv[kk][n] = *(const bf16x8*)(smU + ((kk * 4 + ls) * 128 + wc * 64 + n * 16 + lx) * 8);
    __syncthreads();                           // all reads done before smU becomes kern

    float acc[32];
#pragma unroll
    for (int s = 0; s < 32; ++s) acc[s] = 0.f;

#pragma unroll
    for (int chunk = 0; chunk < 9; ++chunk) {
        // GEMM: rows chunk*64 + wr*32 + [0,32), px wc*64 + [0,64), K=64
        f32x4 ka[2][4];
#pragma unroll
        for (int m = 0; m < 2; ++m)
#pragma unroll
            for (int n = 0; n < 4; ++n) ka[m][n] = f32x4{0.f, 0.f, 0.f, 0.f};
#pragma unroll
        for (int kk = 0; kk < 2; ++kk) {
            bf16x8 a[2];
#pragma unroll
            for (int m = 0; m < 2; ++m)
                a[m] = *(const bf16x8*)(G2p +
                        (size_t)(chunk * 64 + wr * 32 + m * 16 + lx) * 64 + kk * 32 + ls * 8);
#pragma unroll
            for (int n = 0; n < 4; ++n)
#pragma unroll
                for (int m = 0; m < 2; ++m)
                    ka[m][n] = __builtin_amdgcn_mfma_f32_16x16x32_bf16(a[m], bv[kk][n], ka[m][n], 0, 0, 0);
        }
        // epilogue: + g2b, write kern TRANSPOSED [pxl][rl] with 16B-granule XOR swizzle
#pragma unroll
        for (int m = 0; m < 2; ++m) {
            const float4 bb4 = *(const float4*)(g2b + chunk * 64 + wr * 32 + m * 16 + ls * 4);
            const float bb[4] = {bb4.x, bb4.y, bb4.z, bb4.w};
            const int rl0 = wr * 32 + m * 16 + ls * 4;   // multiple of 4
            const int gr = rl0 >> 3, sub = rl0 & 7;      // sub in {0,4}
#pragma unroll
            for (int n = 0; n < 4; ++n) {
                const int pxl = wc * 64 + n * 16 + lx;
                u32x2 pk;
                pk[0] = (unsigned)f2bf(ka[m][n][0] + bb[0]) |
                        ((unsigned)f2bf(ka[m][n][1] + bb[1]) << 16);
                pk[1] = (unsigned)f2bf(ka[m][n][2] + bb[2]) |
                        ((unsigned)f2bf(ka[m][n][3] + bb[3]) << 16);
                *(u32x2*)(smU + pxl * 64 + ((gr ^ (pxl & 7)) << 3) + sub) = pk;
            }
        }
        __syncthreads();
        // load own px column: all 64 rows as 8 b128
        u32x4 kvr[8];
#pragma unroll
        for (int k = 0; k < 8; ++k)
            kvr[k] = *(const u32x4*)(smU + px * 64 + ((k ^ (px & 7)) << 3));
        __syncthreads();                       // kvr done -> smU free; apply overlaps next GEMM
        // apply: rows of this chunk whose channel parity == chalf (c,t compile-time)
#pragma unroll
        for (int rl = 0; rl < 64; ++rl) {
            const int r = chunk * 64 + rl;         // compile-time
            const int c = r / 9, t = r - c * 9;    // compile-time
            const int s = c >> 1;
            if ((c & 1) == chalf) {
                float kv = bfhalf(kvr[rl >> 3][(rl & 7) >> 1], rl & 1);
                float pv = bf2f(smFB[c * 180 + (ty + t / 3) * 18 + tx + (t % 3)]);
                acc[s] = fmaf(kv, pv, acc[s]);
            }
        }
    }

    // ---- fused final 1x1: out = Fw @ concat(ev*(1+sc), fb2) for this 128-px tile ----
#pragma unroll
    for (int s = 0; s < 32; ++s) {
        const int c = 2 * s + chalf;
        acc[s] += bf2f(smFB[c * 180 + (ty + 1) * 18 + (tx + 1)]);
    }
    __syncthreads();                           // all smFB/smU reads done; smA reusable as smF
    // fb2 -> smA octs 8..15
#pragma unroll
    for (int s = 0; s < 32; ++s) {
        const int c = 2 * s + chalf;
        smA[((8 + (c >> 3)) * 128 + px) * 8 + (c & 7)] = f2bf(acc[s]);
    }
    // ev*(1+scale_e) -> smA octs 0..7
#pragma unroll
    for (int it = 0; it < 4; ++it) {
        int i = tid + it * 256;
        int p = i & 127, oct = i >> 7;
        int gy = by + (p >> 4), gx = bx + (p & 15);
        u32x4 v = *(const u32x4*)(evb + ((size_t)(b * 8 + oct) * HW + gy * Wn + gx) * 8);
        float sv = 1.f + scale[(size_t)b * HW + gy * Wn + gx];
#pragma unroll
        for (int q = 0; q < 4; ++q)
            v[q] = (unsigned)f2bf(bfhalf(v[q], 0) * sv) |
                   ((unsigned)f2bf(bfhalf(v[q], 1) * sv) << 16);
        *(u32x4*)(smA + (oct * 128 + p) * 8) = v;
    }
    __syncthreads();

    // GEMM: 128 co x 128 px, K=128; m split in halves for register pressure
    const size_t ob = (size_t)b * 2 * CHW;
#pragma unroll
    for (int mh = 0; mh < 2; ++mh) {
        f32x4 a2[2][4];
#pragma unroll
        for (int m = 0; m < 2; ++m)
#pragma unroll
            for (int n = 0; n < 4; ++n) a2[m][n] = f32x4{0.f, 0.f, 0.f, 0.f};
#pragma unroll
        for (int kk = 0; kk < 4; ++kk) {
            bf16x8 af[2];
#pragma unroll
            for (int m = 0; m < 2; ++m)
                af[m] = *(const bf16x8*)(Fwp +
                        (size_t)(wr * 64 + mh * 32 + m * 16 + lx) * 128 + kk * 32 + ls * 8);
#pragma unroll
            for (int n = 0; n < 4; ++n) {
                bf16x8 bvv = *(const bf16x8*)(smA + ((kk * 4 + ls) * 128 + wc * 64 + n * 16 + lx) * 8);
#pragma unroll
                for (int m = 0; m < 2; ++m)
                    a2[m][n] = __builtin_amdgcn_mfma_f32_16x16x32_bf16(af[m], bvv, a2[m][n], 0, 0, 0);
            }
        }
#pragma unroll
        for (int m = 0; m < 2; ++m)
#pragma unroll
            for (int n = 0; n < 4; ++n) {
                const int pxl = wc * 64 + n * 16 + lx;
                const int gy = by + (pxl >> 4), gx = bx + (pxl & 15);
#pragma unroll
                for (int j = 0; j < 4; ++j) {
                    const int co = wr * 64 + mh * 32 + m * 16 + ls * 4 + j;
                    out[ob + (size_t)co * HW + (size_t)gy * Wn + gx] = a2[m][n][j];
                }
            }
    }
}

// ---------------- host launch ----------------
extern "C" void kernel_launch(void* const* d_in, const int* in_sizes, int n_in,
                              void* d_out, int out_size, void* d_ws, size_t ws_size,
                              hipStream_t stream) {
    const float* f_event = (const float*)d_in[0];
    const float* f_blur  = (const float*)d_in[1];
    const float* Wt1 = (const float*)d_in[2];
    const float* Wt2 = (const float*)d_in[3];
    const float* Wt3 = (const float*)d_in[4];
    const float* A1  = (const float*)d_in[5];
    const float* b1  = (const float*)d_in[6];
    const float* A2  = (const float*)d_in[7];
    const float* b2  = (const float*)d_in[8];
    const float* G1  = (const float*)d_in[9];
    const float* g1b = (const float*)d_in[10];
    const float* G2  = (const float*)d_in[11];
    const float* g2b = (const float*)d_in[12];
    const float* Rw  = (const float*)d_in[13];
    const float* rb  = (const float*)d_in[14];
    const float* S1  = (const float*)d_in[15];
    const float* S2  = (const float*)d_in[16];
    const float* Ew  = (const float*)d_in[17];
    const float* eb  = (const float*)d_in[18];
    const float* Fw  = (const float*)d_in[19];
    float* out = (float*)d_out;

    float* ws    = (float*)d_ws;
    float* w0    = ws;                         // 512
    float* w0s   = w0 + 512;                   // 512
    float* rgb   = w0s + 512;                  // 131072
    float* comp  = rgb + Bn * HW;              // 262144
    float* scale = comp + 2 * Bn * HW;         // 131072
    unsigned short* wprep = (unsigned short*)(scale + Bn * HW);  // 6 x 36864
    unsigned short* G2p = wprep + 6 * 36864;                     // 36864
    unsigned short* Fwp = G2p + 36864;                           // 16384
    unsigned short* zpad = Fwp + 16384;        // 64 shorts (zero page)
    unsigned short* B0 = zpad + 64;            // evblk
    unsigned short* B1 = B0 + NB;              // f0blk
    unsigned short* B2 = B1 + NB;              // t1blk
    unsigned short* B3 = B2 + NB;              // fusedblk
    unsigned short* B4 = B3 + NB;              // hblk
    unsigned short* B5 = B4 + NB;              // fbblk (blocked f_blur)
    unsigned short* B6 = B5 + NB;              // s1blk

    // 0. merged preps + input blocking (one launch)
    prep_all_k<<<5168, 256, 0, stream>>>(f_event, f_blur, B0, B1, B5,
                                         Wt1, Wt2, Wt3, G1, S1, S2, wprep,
                                         G2, Fw, G2p, Fwp, zpad);
    // 1. L1: t1 = relu(conv(f0,Wt1)); h = relu(conv(ev,G1)+g1b); s1 = relu(conv(ev,S1))
    conv3x3_l1_blk<<<dim3(8, 8, 24), 256, 0, stream>>>(
        B1, B0, wprep + 0 * 36864, wprep + 3 * 36864, wprep + 4 * 36864, g1b,
        B2, B4, B6, zpad);
    // 2. L2: fused = conv(t1, Wt2); comp = chan-max/mean(conv(s1, S2))
    conv3x3_l2_blk<<<dim3(8, 8, 16), 256, 0, stream>>>(
        B2, B6, wprep + 1 * 36864, wprep + 5 * 36864, B3, comp, zpad);
    // 3. SE mean
    mean_hw_blk<<<Bn * 8, 256, 0, stream>>>(B3, w0);
    // 4. merged: rgb gate conv (z<8) + sconv5 (8<=z<16) + SE MLP (z==16)
    rgb_sconv_mlp_k<<<dim3(8, 8, 17), 256, 0, stream>>>(
        B3, wprep + 2 * 36864, Rw, rb, rgb, comp, Ew, eb, scale, zpad,
        w0, A1, b1, A2, b2, w0s);
    // 5. fb2 = fb1 + dynconv(fb1, kern(h)); then out = Fw @ concat(ev*(1+sc), fb2)
    dynfused_k<<<dim3(8, 16, Bn), 256, 0, stream>>>(
        B5, B4, G2p, g2b, w0s, rgb, B0, scale, Fwp, out);
}